// Round 19
// baseline (34190.439 us; speedup 1.0000x reference)
//
#include <hip/hip_runtime.h>
#include <cmath>

#define NN 128
#define TT 20
#define ERNN 256
#define TEMPSC 15.875f /* (N-1)/sqrt(ATT) = 127/8 */

typedef __attribute__((ext_vector_type(8))) short bf16x8;
typedef __attribute__((ext_vector_type(4))) float f32x4;

__device__ __forceinline__ float sigm(float x){ return 1.f/(1.f+__expf(-x)); }
__device__ __forceinline__ float ftanh(float x){ float e = __expf(2.f*x); return 1.f - 2.f/(e + 1.f); }
__device__ __forceinline__ float b2f(unsigned short u){ union{unsigned int i; float f;} v; v.i = ((unsigned int)u)<<16; return v.f; }
__device__ __forceinline__ unsigned short f2b(float x){ union{float f; unsigned int u;} v; v.f = x; unsigned int r = v.u + 0x7fffu + ((v.u>>16)&1u); return (unsigned short)(r>>16); }

typedef __attribute__((address_space(3))) unsigned int lds_u32;
typedef __attribute__((address_space(1))) unsigned int glb_u32;
__device__ __forceinline__ void glds16(const void* g, void* l){
    __builtin_amdgcn_global_load_lds((const glb_u32*)g, (lds_u32*)l, 16, 0, 0);
}

// chunked h: [tile=r>>7][kc=d>>3 (32)][row=r&127][q=d&7]
__device__ __forceinline__ size_t hoff(int r, int d){
    return ((size_t)((r>>7)*32 + (d>>3))*128 + (r&127))*8 + (d&7);
}

// timeout-bounded acquire spin: returns false on timeout (abort instead of hang)
__device__ __forceinline__ bool spin_ge(int* f, int target){
    for (long k = 0; k < 50000000L; ++k) {
        if (__hip_atomic_load(f, __ATOMIC_ACQUIRE, __HIP_MEMORY_SCOPE_AGENT) >= target) return true;
        __builtin_amdgcn_s_sleep(8);
    }
    return false;
}

// ---- one mega-prep kernel ----
#define R_W2    (2*1024*320)
#define R_EB    2048
#define R_NWT   131072
#define R_NBS   512
#define R_HNN   16384
#define R_CNN   16384
#define R_INIT  (16384*32)
#define R_XENC  ((size_t)TT*16384*8)
#define PREP_TOT (R_W2 + R_EB + R_NWT + R_NBS + R_HNN + R_CNNN_ + 0)
#undef PREP_TOT
#define PREP_TOT (R_W2 + R_EB + R_NWT + R_NBS + R_HNN + R_CNN + R_INIT + R_XENC)

__global__ void k_prep_all(
    const float* __restrict__ s_wih, const float* __restrict__ s_whh, unsigned short* __restrict__ s_wHi,
    const float* __restrict__ t_wih, const float* __restrict__ t_whh, unsigned short* __restrict__ t_wHi,
    const float* __restrict__ s_bih, const float* __restrict__ s_bhh, float* __restrict__ s_bs,
    const float* __restrict__ t_bih, const float* __restrict__ t_bhh, float* __restrict__ t_bs,
    const float* __restrict__ n_wih, const float* __restrict__ n_whh, float* __restrict__ n_wT,
    const float* __restrict__ n_bih, const float* __restrict__ n_bhh, float* __restrict__ n_bs,
    const float* __restrict__ h_n0, float* __restrict__ h_nn,
    const float* __restrict__ c_n0, float* __restrict__ c_nn,
    const float* __restrict__ h_e0, unsigned short* __restrict__ hHi,
    const float* __restrict__ edges,
    const float* __restrict__ s_enc_w, const float* __restrict__ s_enc_b,
    const float* __restrict__ t_enc_w, const float* __restrict__ t_enc_b,
    unsigned short* __restrict__ xe)
{
    size_t i = (size_t)blockIdx.x*256 + threadIdx.x;
    if (i < R_W2) {
        int idx = (int)i;
        int which = idx >= 1024*320;
        if (which) idx -= 1024*320;
        const float* wih = which ? t_wih : s_wih;
        const float* whh = which ? t_whh : s_whh;
        unsigned short* wHi = which ? t_wHi : s_wHi;
        int c = idx / 320, k = idx - c*320;
        int ch = ((c>>6)<<4) + (c&15), g = (c>>4)&3;
        int r = g*256 + ch;
        float v = (k < 64) ? wih[r*64 + k] : whh[r*256 + (k-64)];
        size_t dst = ((size_t)((c>>7)*40 + (k>>3))*128 + (c&127))*8 + (k&7);
        wHi[dst] = f2b(v);
        return;
    }
    i -= R_W2;
    if (i < R_EB) {
        int c = (int)i, which = c >= 1024;
        if (which) c -= 1024;
        const float* bih = which ? t_bih : s_bih;
        const float* bhh = which ? t_bhh : s_bhh;
        float* bs = which ? t_bs : s_bs;
        int ch = ((c>>6)<<4)+(c&15), g=(c>>4)&3;
        int r = g*256+ch;
        bs[c] = bih[r] + bhh[r];
        return;
    }
    i -= R_EB;
    if (i < R_NWT) {
        int j = (int)i;
        if (j < 65536) { int r = j >> 7, c = j & 127; n_wT[c*512 + r] = n_wih[j]; }
        else { j -= 65536; int r = j >> 7, c = j & 127; n_wT[(128 + c)*512 + r] = n_whh[j]; }
        return;
    }
    i -= R_NWT;
    if (i < R_NBS) { n_bs[i] = n_bih[i] + n_bhh[i]; return; }
    i -= R_NBS;
    if (i < R_HNN) { h_nn[i] = h_n0[i]; return; }
    i -= R_HNN;
    if (i < R_CNN) { c_nn[i] = c_n0[i]; return; }
    i -= R_CNN;
    if (i < R_INIT) {
        int g = (int)i;
        int d8 = g & 31, r = g >> 5;
        int row_ij;
        if (r < 16256){ int ii = r/127, jj = r - ii*127; row_ij = ii*NN + jj + (jj>=ii ? 1:0); }
        else          { row_ij = (r - 16256)*(NN+1); }
        const float* hs = h_e0 + (size_t)row_ij*ERNN + d8*8;
        bf16x8 hb;
        #pragma unroll
        for (int q = 0; q < 8; ++q) hb[q] = (short)f2b(hs[q]);
        *(bf16x8*)&hHi[hoff(r, d8*8)] = hb;
        return;
    }
    i -= R_INIT;
    if (i < R_XENC) {
        size_t g = i;
        int row = (int)(g & 127);
        size_t rest = g >> 7;
        int kc = (int)(rest & 7);
        int tile = (int)((rest >> 3) & 127);
        int t = (int)(rest >> 10);
        int r = tile*128 + row;
        bool sp = (r < 16256);
        int row_ij;
        if (sp) { int ii = r/127, jj = r - ii*127; row_ij = ii*NN + jj + (jj>=ii ? 1:0); }
        else    { row_ij = (r - 16256)*(NN+1); }
        const float* w = sp ? s_enc_w : t_enc_w;
        const float* b = sp ? s_enc_b : t_enc_b;
        float e0 = edges[((size_t)t*16384 + row_ij)*2];
        float e1 = edges[((size_t)t*16384 + row_ij)*2 + 1];
        bf16x8 v8;
        #pragma unroll
        for (int q = 0; q < 8; ++q) {
            int m = kc*8 + q;
            v8[q] = (short)f2b(fmaxf(fmaf(w[m*2], e0, fmaf(w[m*2+1], e1, b[m])), 0.f));
        }
        *(bf16x8*)&xe[g*8] = v8;
    }
}

struct PP {
    const unsigned short *xenc;
    unsigned short *h_a, *h_b, *hl_a, *hl_b;
    const float *c_e0;
    const unsigned short *s_wHi, *t_wHi;
    const float *s_bs, *t_bs;
    const float *nodes;
    float *h_nn, *c_nn, *outp;
    const float *att_t_w, *att_t_b, *att_s_w, *att_s_b;
    const float *n_enc_w, *n_enc_b, *n_attn_w, *n_attn_b, *n_wT, *n_bs, *out_w, *out_b;
    int *flags;   // [128] group flags + [1] node counter
};

#define ESTEP(KS, NW) do { \
    asm volatile("s_waitcnt vmcnt(" #NW ")" ::: "memory"); \
    __builtin_amdgcn_s_barrier(); \
    __builtin_amdgcn_sched_barrier(0); \
    bf16x8 a0 = *(const bf16x8*)&Ah[(KS)&1][(kg*128 + arow)*8]; \
    bf16x8 a1 = *(const bf16x8*)&Ah[(KS)&1][(kg*128 + arow + 16)*8]; \
    bf16x8 b0 = *(const bf16x8*)&Bh[(KS)&1][(kg*128 + bcol)*8]; \
    bf16x8 b1 = *(const bf16x8*)&Bh[(KS)&1][(kg*128 + bcol + 16)*8]; \
    bf16x8 b2 = *(const bf16x8*)&Bh[(KS)&1][(kg*128 + bcol + 32)*8]; \
    bf16x8 b3 = *(const bf16x8*)&Bh[(KS)&1][(kg*128 + bcol + 48)*8]; \
    asm volatile("s_waitcnt lgkmcnt(0)" ::: "memory"); \
    __builtin_amdgcn_sched_barrier(0); \
    __builtin_amdgcn_s_barrier(); \
    if ((KS) + 2 <= 9) stage((KS)+2, (KS)&1); \
    acc[0][0] = __builtin_amdgcn_mfma_f32_16x16x32_bf16(a0, b0, acc[0][0],0,0,0); \
    acc[0][1] = __builtin_amdgcn_mfma_f32_16x16x32_bf16(a0, b1, acc[0][1],0,0,0); \
    acc[0][2] = __builtin_amdgcn_mfma_f32_16x16x32_bf16(a0, b2, acc[0][2],0,0,0); \
    acc[0][3] = __builtin_amdgcn_mfma_f32_16x16x32_bf16(a0, b3, acc[0][3],0,0,0); \
    acc[1][0] = __builtin_amdgcn_mfma_f32_16x16x32_bf16(a1, b0, acc[1][0],0,0,0); \
    acc[1][1] = __builtin_amdgcn_mfma_f32_16x16x32_bf16(a1, b1, acc[1][1],0,0,0); \
    acc[1][2] = __builtin_amdgcn_mfma_f32_16x16x32_bf16(a1, b2, acc[1][2],0,0,0); \
    acc[1][3] = __builtin_amdgcn_mfma_f32_16x16x32_bf16(a1, b3, acc[1][3],0,0,0); \
} while(0)

// Persistent kernel (plain launch): all 20 steps, 1024 blocks x 512 threads =
// exactly 4 blocks/CU resident (launch_bounds caps VGPR at 64; LDS 32KB).
// Sync: per-bm-group device-scope flags; node(t) runs in the ntp==0 owner block.
// All spins timeout -> clean abort instead of hang.
__global__ __launch_bounds__(512, 8) void k_persist(PP p)
{
    __shared__ __align__(16) char smem[32768];
    __shared__ int dead;
    const int bid = blockIdx.x, tid = threadIdx.x;
    const int lane = tid & 63, wid = tid >> 6;
    const int wg = (bid & 7)*128 + (bid >> 3);     // XCD swizzle, bijective on 1024
    const int bm = wg >> 3, ntp = wg & 7;
    const bool sp = (bm < 127);
    const int rbase = bm * 128;
    const unsigned short* wHi = sp ? p.s_wHi : p.t_wHi;
    const float* bs = sp ? p.s_bs : p.t_bs;
    const int wr = wid & 3, wc = wid >> 2;
    const int nt = ntp*2 + wc;
    const bool owner = (ntp == 0);                 // node index = bm
    unsigned short (*Ah)[4096] = (unsigned short(*)[4096])smem;
    unsigned short (*Bh)[4096] = (unsigned short(*)[4096])(smem + 16384);
    const int arow = wr*32 + (lane & 15);
    const int bcol = wc*64 + (lane & 15);
    const int kg = lane >> 4;
    const int chl = lane & 15, q4 = (lane >> 4)*4;
    const int ch = nt*16 + chl;
    const int cbase = nt*64 + chl;
    const float b0g = bs[cbase], b1g = bs[cbase+16], b2g = bs[cbase+32], b3g = bs[cbase+48];
    int* flags = p.flags;
    int* ncnt  = p.flags + 128;
    if (tid == 0) dead = 0;

    // c-state in registers (fp32, exact), thread-exclusive across all steps
    float creg[2][4];
    #pragma unroll
    for (int m = 0; m < 2; ++m)
        #pragma unroll
        for (int rg = 0; rg < 4; ++rg) {
            int r = rbase + wr*32 + m*16 + q4 + rg;
            int row_ij;
            if (r < 16256){ int ii = r/127, jj = r - ii*127; row_ij = ii*NN + jj + (jj>=ii ? 1:0); }
            else          { row_ij = (r - 16256)*(NN+1); }
            creg[m][rg] = p.c_e0[(size_t)row_ij*ERNN + ch];
        }

    for (int t = 0; t < TT; ++t) {
        const unsigned short* h_in = (t & 1) ? p.h_b : p.h_a;
        unsigned short* h_out  = (t & 1) ? p.h_a : p.h_b;
        unsigned short* hl_out = (t & 1) ? p.hl_b : p.hl_a;
        const unsigned short* xenc_t = p.xenc + (size_t)t*16384*64;

        if (t > 0) { if (tid == 0 && !spin_ge(flags + bm, 8*t)) dead = 1; }
        __syncthreads();
        if (dead) return;

        auto stage = [&](int ks, int b){
            int kc = wid >> 1, half = wid & 1;
            const unsigned short* asrc = (ks < 2)
                ? xenc_t + ((size_t)bm*8  + ks*4     + kc)*1024 + half*512
                : h_in   + ((size_t)bm*32 + (ks-2)*4 + kc)*1024 + half*512;
            glds16(asrc + lane*8, (char*)&Ah[b][0] + wid*1024);
            size_t wb = ((size_t)(ntp*40 + ks*4 + kc)*128 + half*64)*8;
            glds16(wHi + wb + lane*8, (char*)&Bh[b][0] + wid*1024);
        };
        stage(0, 0);
        stage(1, 1);

        f32x4 acc[2][4];
        #pragma unroll
        for (int m = 0; m < 2; ++m)
            #pragma unroll
            for (int g = 0; g < 4; ++g)
                acc[m][g] = (f32x4){0.f,0.f,0.f,0.f};

        ESTEP(0, 2); ESTEP(1, 2); ESTEP(2, 2); ESTEP(3, 2); ESTEP(4, 2);
        ESTEP(5, 2); ESTEP(6, 2); ESTEP(7, 2); ESTEP(8, 2); ESTEP(9, 0);

        // hl(t) overwrites hl(t-2): ensure node(t-2) readers are done
        if (t >= 2) { if (tid == 0 && !spin_ge(ncnt, 128*(t-1))) dead = 1; }
        __syncthreads();
        if (dead) return;

        #pragma unroll
        for (int m = 0; m < 2; ++m) {
            #pragma unroll
            for (int rg = 0; rg < 4; ++rg) {
                int lrow = wr*32 + m*16 + q4 + rg;
                int row = rbase + lrow;
                float gi = acc[m][0][rg] + b0g;
                float gf = acc[m][1][rg] + b1g;
                float gg = acc[m][2][rg] + b2g;
                float go = acc[m][3][rg] + b3g;
                float c2 = sigm(gf)*creg[m][rg] + sigm(gi)*ftanh(gg);
                float h2 = sigm(go)*ftanh(c2);
                creg[m][rg] = c2;
                unsigned short hb = f2b(h2);
                h_out[((size_t)(bm*32 + (ch>>3))*128 + lrow)*8 + (ch&7)] = hb;
                hl_out[(size_t)row*256 + ch] = hb;
            }
        }
        __syncthreads();   // all waves' stores drained before the release
        if (tid == 0)
            __hip_atomic_fetch_add(flags + bm, 1, __ATOMIC_RELEASE, __HIP_MEMORY_SCOPE_AGENT);

        if (owner) {
            // ---- node i = bm at step t: reads hl_out(t) of <=2 groups + group 127 ----
            const int i = bm;
            const unsigned short* hl = hl_out;
            if (tid == 0) {
                int t1 = (i*127) >> 7, t2 = (i*127 + 126) >> 7;
                bool ok = spin_ge(flags + t1, 8*(t+1));
                if (ok && t2 != t1) ok = spin_ge(flags + t2, 8*(t+1));
                if (ok) ok = spin_ge(flags + 127, 8*(t+1));
                if (!ok) dead = 1;
            }
            __syncthreads();
            if (dead) return;
            float* sm  = (float*)smem;
            float* ht  = sm;           float* te  = sm + 256;
            float* u   = sm + 320;     float* lg  = sm + 576;
            float* cat = sm + 704;     float* xc  = sm + 1216;
            float* hnl = sm + 1344;    float* gl  = sm + 1472;
            float* pws = sm + 1984;    float* msc = sm + 4032;
            const float* nodes_t = p.nodes + (size_t)t*NN*2;
            float* out_t = p.outp + (size_t)t*NN*5;

            if (tid < 256) ht[tid] = b2f(hl[(size_t)(16256 + i)*256 + tid]);
            __syncthreads();
            if (tid < 256) {
                int m = tid >> 2, q = tid & 3;
                float s = 0.f;
                const float* wr2 = p.att_t_w + m*ERNN + q*64;
                const float* hh = ht + q*64;
                #pragma unroll 8
                for (int k = 0; k < 64; ++k) s = fmaf(wr2[k], hh[k], s);
                s += __shfl_xor(s, 1);
                s += __shfl_xor(s, 2);
                if (q == 0) te[m] = s + p.att_t_b[m];
            }
            __syncthreads();
            if (tid < 256) {
                float s = 0.f;
                for (int m = 0; m < 64; ++m) s = fmaf(p.att_s_w[m*ERNN + tid], te[m], s);
                u[tid] = s;
            }
            if (tid == 320) {
                float s = 0.f;
                for (int m = 0; m < 64; ++m) s = fmaf(te[m], p.att_s_b[m], s);
                msc[2] = s;
            }
            __syncthreads();
            {
                int slot = tid >> 2, q = tid & 3;
                float part = 0.f;
                if (slot < 127) {
                    const unsigned short* hs = hl + (size_t)(i*127 + slot)*256 + q*64;
                    const float* uu = u + q*64;
                    #pragma unroll
                    for (int d8 = 0; d8 < 8; ++d8) {
                        bf16x8 v = *(const bf16x8*)(hs + d8*8);
                        #pragma unroll
                        for (int j = 0; j < 8; ++j)
                            part = fmaf(uu[d8*8 + j], b2f((unsigned short)v[j]), part);
                    }
                }
                part += __shfl_xor(part, 1);
                part += __shfl_xor(part, 2);
                if (slot < 127 && q == 0) lg[slot] = (part + msc[2]) * TEMPSC;
                if (tid == 511) lg[127] = -1e30f;
            }
            __syncthreads();
            if (tid < 64) {
                float a = fmaxf(lg[tid], lg[tid+64]);
                for (int off = 32; off; off >>= 1) a = fmaxf(a, __shfl_xor(a, off));
                if (tid == 0) msc[0] = a;
            }
            __syncthreads();
            if (tid < 128) lg[tid] = (tid < 127) ? __expf(lg[tid] - msc[0]) : 0.f;
            __syncthreads();
            if (tid < 64) {
                float a = lg[tid] + lg[tid+64];
                for (int off = 32; off; off >>= 1) a += __shfl_xor(a, off);
                if (tid == 0) msc[1] = a;
            }
            __syncthreads();
            {
                int w = tid >> 6, ln = tid & 63;
                float a0 = 0.f, a1 = 0.f, a2 = 0.f, a3 = 0.f;
                #pragma unroll 4
                for (int s = w*16; s < w*16 + 16; ++s) {
                    int srow = (s < 127) ? s : 0;
                    float wgt = lg[s];
                    const unsigned short* hs = hl + (size_t)(i*127 + srow)*256 + ln*4;
                    ushort4 v = *(const ushort4*)hs;
                    a0 = fmaf(wgt, b2f(v.x), a0);
                    a1 = fmaf(wgt, b2f(v.y), a1);
                    a2 = fmaf(wgt, b2f(v.z), a2);
                    a3 = fmaf(wgt, b2f(v.w), a3);
                }
                pws[w*256 + ln*4+0] = a0; pws[w*256 + ln*4+1] = a1;
                pws[w*256 + ln*4+2] = a2; pws[w*256 + ln*4+3] = a3;
            }
            if (tid >= 256 && tid < 384) hnl[tid-256] = p.h_nn[i*128 + (tid-256)];
            __syncthreads();
            if (tid < 256) {
                float s = 0.f;
                #pragma unroll
                for (int w = 0; w < 8; ++w) s += pws[w*256 + tid];
                cat[256 + tid] = s / msc[1];
                cat[tid] = ht[tid];
            }
            __syncthreads();
            if (tid < 64) {
                float p0 = nodes_t[i*2], p1 = nodes_t[i*2+1];
                xc[tid] = fmaxf(fmaf(p.n_enc_w[tid*2], p0, fmaf(p.n_enc_w[tid*2+1], p1, p.n_enc_b[tid])), 0.f);
            }
            if (tid >= 256) {
                int t2 = tid - 256;
                int m = t2 >> 2, q = t2 & 3;
                float s = 0.f;
                const float* wr2 = p.n_attn_w + m*512 + q*128;
                const float* cc = cat + q*128;
                #pragma unroll 8
                for (int d = 0; d < 128; ++d) s = fmaf(wr2[d], cc[d], s);
                s += __shfl_xor(s, 1);
                s += __shfl_xor(s, 2);
                if (q == 0) xc[64 + m] = fmaxf(s + p.n_attn_b[m], 0.f);
            }
            __syncthreads();
            {
                int n = tid;
                float s = p.n_bs[n];
                for (int k = 0; k < 128; ++k) s = fmaf(p.n_wT[k*512 + n], xc[k], s);
                for (int k = 0; k < 128; ++k) s = fmaf(p.n_wT[(128+k)*512 + n], hnl[k], s);
                gl[n] = s;
            }
            __syncthreads();
            if (tid < 128) {
                float co = p.c_nn[i*128 + tid];
                float c2 = sigm(gl[128+tid])*co + sigm(gl[tid])*ftanh(gl[256+tid]);
                float h2 = sigm(gl[384+tid])*ftanh(c2);
                p.c_nn[i*128+tid] = c2;
                p.h_nn[i*128+tid] = h2;
                hnl[tid] = h2;
            }
            __syncthreads();
            if (tid < 5) {
                float s = p.out_b[tid];
                const float* wr2 = p.out_w + tid*128;
                for (int k = 0; k < 128; ++k) s = fmaf(wr2[k], hnl[k], s);
                out_t[i*5 + tid] = s;
            }
            __syncthreads();   // node stores drained before counting
            if (tid == 0)
                __hip_atomic_fetch_add(ncnt, 1, __ATOMIC_RELEASE, __HIP_MEMORY_SCOPE_AGENT);
        }
    }
}

extern "C" void kernel_launch(void* const* d_in, const int* in_sizes, int n_in,
                              void* d_out, int out_size, void* d_ws, size_t ws_size,
                              hipStream_t stream)
{
    const float* nodes   = (const float*)d_in[0];
    const float* edges   = (const float*)d_in[1];
    const float* h_e0    = (const float*)d_in[2];
    const float* c_e0    = (const float*)d_in[3];
    const float* h_n0    = (const float*)d_in[4];
    const float* c_n0    = (const float*)d_in[5];
    const float* t_enc_w = (const float*)d_in[6];
    const float* t_enc_b = (const float*)d_in[7];
    const float* t_wih   = (const float*)d_in[8];
    const float* t_whh   = (const float*)d_in[9];
    const float* t_bih   = (const float*)d_in[10];
    const float* t_bhh   = (const float*)d_in[11];
    const float* s_enc_w = (const float*)d_in[12];
    const float* s_enc_b = (const float*)d_in[13];
    const float* s_wih   = (const float*)d_in[14];
    const float* s_whh   = (const float*)d_in[15];
    const float* s_bih   = (const float*)d_in[16];
    const float* s_bhh   = (const float*)d_in[17];
    const float* att_t_w = (const float*)d_in[18];
    const float* att_t_b = (const float*)d_in[19];
    const float* att_s_w = (const float*)d_in[20];
    const float* att_s_b = (const float*)d_in[21];
    const float* n_enc_w = (const float*)d_in[22];
    const float* n_enc_b = (const float*)d_in[23];
    const float* n_attn_w= (const float*)d_in[24];
    const float* n_attn_b= (const float*)d_in[25];
    const float* n_wih   = (const float*)d_in[26];
    const float* n_whh   = (const float*)d_in[27];
    const float* n_bih   = (const float*)d_in[28];
    const float* n_bhh   = (const float*)d_in[29];
    const float* out_w   = (const float*)d_in[30];
    const float* out_b   = (const float*)d_in[31];
    float* out = (float*)d_out;

    char* p = (char*)d_ws;
    float* h_nn  = (float*)p;            p += 128*128*4;
    float* c_nn  = (float*)p;            p += 128*128*4;
    float* s_bs  = (float*)p;            p += 1024*4;
    float* t_bs  = (float*)p;            p += 1024*4;
    float* n_wT  = (float*)p;            p += 256*512*4;
    float* n_bs  = (float*)p;            p += 512*4;
    int*   flags = (int*)p;              p += 256*4;
    unsigned short* h_a  = (unsigned short*)p;  p += (size_t)16384*256*2;
    unsigned short* h_b  = (unsigned short*)p;  p += (size_t)16384*256*2;
    unsigned short* hl_a = (unsigned short*)p;  p += (size_t)16384*256*2;
    unsigned short* hl_b = (unsigned short*)p;  p += (size_t)16384*256*2;
    unsigned short* xenc = (unsigned short*)p;  p += (size_t)TT*16384*64*2;
    unsigned short* s_wHi = (unsigned short*)p; p += 1024*320*2;
    unsigned short* t_wHi = (unsigned short*)p; p += 1024*320*2;

    hipMemsetAsync(flags, 0, 256*sizeof(int), stream);

    int prep_blocks = (int)((PREP_TOT + 255) / 256);
    k_prep_all<<<prep_blocks, 256, 0, stream>>>(
        s_wih, s_whh, s_wHi, t_wih, t_whh, t_wHi,
        s_bih, s_bhh, s_bs, t_bih, t_bhh, t_bs,
        n_wih, n_whh, n_wT, n_bih, n_bhh, n_bs,
        h_n0, h_nn, c_n0, c_nn,
        h_e0, h_a,
        edges, s_enc_w, s_enc_b, t_enc_w, t_enc_b, xenc);

    PP pp;
    pp.xenc = xenc; pp.h_a = h_a; pp.h_b = h_b; pp.hl_a = hl_a; pp.hl_b = hl_b;
    pp.c_e0 = c_e0;
    pp.s_wHi = s_wHi; pp.t_wHi = t_wHi; pp.s_bs = s_bs; pp.t_bs = t_bs;
    pp.nodes = nodes; pp.h_nn = h_nn; pp.c_nn = c_nn; pp.outp = out;
    pp.att_t_w = att_t_w; pp.att_t_b = att_t_b; pp.att_s_w = att_s_w; pp.att_s_b = att_s_b;
    pp.n_enc_w = n_enc_w; pp.n_enc_b = n_enc_b; pp.n_attn_w = n_attn_w; pp.n_attn_b = n_attn_b;
    pp.n_wT = n_wT; pp.n_bs = n_bs; pp.out_w = out_w; pp.out_b = out_b;
    pp.flags = flags;

    k_persist<<<1024, 512, 0, stream>>>(pp);
}

// Round 20
// 1226.269 us; speedup vs baseline: 27.8817x; 27.8817x over previous
//
#include <hip/hip_runtime.h>
#include <cmath>

#define NN 128
#define TT 20
#define ERNN 256
#define TEMPSC 15.875f /* (N-1)/sqrt(ATT) = 127/8 */

typedef __attribute__((ext_vector_type(8))) short bf16x8;
typedef __attribute__((ext_vector_type(4))) float f32x4;

__device__ __forceinline__ float sigm(float x){ return 1.f/(1.f+__expf(-x)); }
__device__ __forceinline__ float ftanh(float x){ float e = __expf(2.f*x); return 1.f - 2.f/(e + 1.f); }
__device__ __forceinline__ float b2f(unsigned short u){ union{unsigned int i; float f;} v; v.i = ((unsigned int)u)<<16; return v.f; }
__device__ __forceinline__ unsigned short f2b(float x){ union{float f; unsigned int u;} v; v.f = x; unsigned int r = v.u + 0x7fffu + ((v.u>>16)&1u); return (unsigned short)(r>>16); }

typedef __attribute__((address_space(3))) unsigned int lds_u32;
typedef __attribute__((address_space(1))) unsigned int glb_u32;
__device__ __forceinline__ void glds16(const void* g, void* l){
    __builtin_amdgcn_global_load_lds((const glb_u32*)g, (lds_u32*)l, 16, 0, 0);
}

// chunked h: [tile=r>>7][kc=d>>3 (32)][row=r&127][q=d&7]
__device__ __forceinline__ size_t hoff(int r, int d){
    return ((size_t)((r>>7)*32 + (d>>3))*128 + (r&127))*8 + (d&7);
}

// ---- one mega-prep kernel ----
#define R_W2    (2*1024*320)
#define R_EB    2048
#define R_NWT   131072
#define R_NBS   512
#define R_HNN   16384
#define R_CNN   16384
#define R_INIT  (16384*32)
#define R_XENC  ((size_t)TT*16384*8)
#define PREP_TOT (R_W2 + R_EB + R_NWT + R_NBS + R_HNN + R_CNN + R_INIT + R_XENC)

__global__ void k_prep_all(
    const float* __restrict__ s_wih, const float* __restrict__ s_whh, unsigned short* __restrict__ s_wHi,
    const float* __restrict__ t_wih, const float* __restrict__ t_whh, unsigned short* __restrict__ t_wHi,
    const float* __restrict__ s_bih, const float* __restrict__ s_bhh, float* __restrict__ s_bs,
    const float* __restrict__ t_bih, const float* __restrict__ t_bhh, float* __restrict__ t_bs,
    const float* __restrict__ n_wih, const float* __restrict__ n_whh, float* __restrict__ n_wT,
    const float* __restrict__ n_bih, const float* __restrict__ n_bhh, float* __restrict__ n_bs,
    const float* __restrict__ h_n0, float* __restrict__ h_nn,
    const float* __restrict__ c_n0, float* __restrict__ c_nn,
    const float* __restrict__ h_e0, const float* __restrict__ c_e0,
    unsigned short* __restrict__ hHi, unsigned short* __restrict__ c_b,
    const float* __restrict__ edges,
    const float* __restrict__ s_enc_w, const float* __restrict__ s_enc_b,
    const float* __restrict__ t_enc_w, const float* __restrict__ t_enc_b,
    unsigned short* __restrict__ xe)
{
    size_t i = (size_t)blockIdx.x*256 + threadIdx.x;
    if (i < R_W2) {
        int idx = (int)i;
        int which = idx >= 1024*320;
        if (which) idx -= 1024*320;
        const float* wih = which ? t_wih : s_wih;
        const float* whh = which ? t_whh : s_whh;
        unsigned short* wHi = which ? t_wHi : s_wHi;
        int c = idx / 320, k = idx - c*320;
        int ch = ((c>>6)<<4) + (c&15), g = (c>>4)&3;
        int r = g*256 + ch;
        float v = (k < 64) ? wih[r*64 + k] : whh[r*256 + (k-64)];
        size_t dst = ((size_t)((c>>7)*40 + (k>>3))*128 + (c&127))*8 + (k&7);
        wHi[dst] = f2b(v);
        return;
    }
    i -= R_W2;
    if (i < R_EB) {
        int c = (int)i, which = c >= 1024;
        if (which) c -= 1024;
        const float* bih = which ? t_bih : s_bih;
        const float* bhh = which ? t_bhh : s_bhh;
        float* bs = which ? t_bs : s_bs;
        int ch = ((c>>6)<<4)+(c&15), g=(c>>4)&3;
        int r = g*256+ch;
        bs[c] = bih[r] + bhh[r];
        return;
    }
    i -= R_EB;
    if (i < R_NWT) {
        int j = (int)i;
        if (j < 65536) { int r = j >> 7, c = j & 127; n_wT[c*512 + r] = n_wih[j]; }
        else { j -= 65536; int r = j >> 7, c = j & 127; n_wT[(128 + c)*512 + r] = n_whh[j]; }
        return;
    }
    i -= R_NWT;
    if (i < R_NBS) { n_bs[i] = n_bih[i] + n_bhh[i]; return; }
    i -= R_NBS;
    if (i < R_HNN) { h_nn[i] = h_n0[i]; return; }
    i -= R_HNN;
    if (i < R_CNN) { c_nn[i] = c_n0[i]; return; }
    i -= R_CNN;
    if (i < R_INIT) {
        int g = (int)i;
        int d8 = g & 31, r = g >> 5;
        int row_ij;
        if (r < 16256){ int ii = r/127, jj = r - ii*127; row_ij = ii*NN + jj + (jj>=ii ? 1:0); }
        else          { row_ij = (r - 16256)*(NN+1); }
        const float* hs = h_e0 + (size_t)row_ij*ERNN + d8*8;
        const float* cs = c_e0 + (size_t)row_ij*ERNN + d8*8;
        bf16x8 hb, cb;
        #pragma unroll
        for (int q = 0; q < 8; ++q){ hb[q] = (short)f2b(hs[q]); cb[q] = (short)f2b(cs[q]); }
        *(bf16x8*)&hHi[hoff(r, d8*8)] = hb;
        *(bf16x8*)&c_b[(size_t)r*ERNN + d8*8] = cb;
        return;
    }
    i -= R_INIT;
    if (i < R_XENC) {
        size_t g = i;
        int row = (int)(g & 127);
        size_t rest = g >> 7;
        int kc = (int)(rest & 7);
        int tile = (int)((rest >> 3) & 127);
        int t = (int)(rest >> 10);
        int r = tile*128 + row;
        bool sp = (r < 16256);
        int row_ij;
        if (sp) { int ii = r/127, jj = r - ii*127; row_ij = ii*NN + jj + (jj>=ii ? 1:0); }
        else    { row_ij = (r - 16256)*(NN+1); }
        const float* w = sp ? s_enc_w : t_enc_w;
        const float* b = sp ? s_enc_b : t_enc_b;
        float e0 = edges[((size_t)t*16384 + row_ij)*2];
        float e1 = edges[((size_t)t*16384 + row_ij)*2 + 1];
        bf16x8 v8;
        #pragma unroll
        for (int q = 0; q < 8; ++q) {
            int m = kc*8 + q;
            v8[q] = (short)f2b(fmaxf(fmaf(w[m*2], e0, fmaf(w[m*2+1], e1, b[m])), 0.f));
        }
        *(bf16x8*)&xe[g*8] = v8;
    }
}

// Fused per-step, 256 threads, 8 blocks/CU:
//   blocks [0,128)      = node step t-1 (R8-style fp32 body, reads hf_prev)
//   blocks [128,128+2048)= edge GEMM step t (R12 body: BM128xBN64, 12KB LDS)
__global__ __launch_bounds__(256, 8) void k_fused(
    const unsigned short* __restrict__ xenc_t,
    const unsigned short* __restrict__ h_in, unsigned short* __restrict__ h_out,
    float* __restrict__ hf_out, unsigned short* __restrict__ c_b,
    const unsigned short* __restrict__ s_wHi, const float* __restrict__ s_bs,
    const unsigned short* __restrict__ t_wHi, const float* __restrict__ t_bs,
    int has_node, int n_edge,
    const float* __restrict__ nodes_prev, const float* __restrict__ hf_prev,
    float* __restrict__ h_nn, float* __restrict__ c_nn, float* __restrict__ out_prev,
    const float* __restrict__ att_t_w, const float* __restrict__ att_t_b,
    const float* __restrict__ att_s_w, const float* __restrict__ att_s_b,
    const float* __restrict__ n_enc_w, const float* __restrict__ n_enc_b,
    const float* __restrict__ n_attn_w, const float* __restrict__ n_attn_b,
    const float* __restrict__ n_wT, const float* __restrict__ n_bsum,
    const float* __restrict__ out_w, const float* __restrict__ out_b)
{
    __shared__ __align__(16) char smem[12544];
    const int bid = blockIdx.x, tid = threadIdx.x;

    if (bid < NN) {
        // ================= node path (step t-1), 256 threads, fp32 reads ========
        if (!has_node) return;
        const int i = bid;
        float* sm  = (float*)smem;
        float* ht  = sm;          // 256
        float* te  = sm + 256;    // 64
        float* u   = sm + 320;    // 256
        float* lg  = sm + 576;    // 128
        float* cat = sm + 704;    // 512
        float* xc  = sm + 1216;   // 128
        float* hnl = sm + 1344;   // 128
        float* gl  = sm + 1472;   // 512
        float* msc = sm + 1984;   // smax, ssum, c0s
        const float* h = hf_prev;

        ht[tid] = h[(size_t)(16256 + i)*256 + tid];
        __syncthreads();
        if (tid < 64) {
            float s = att_t_b[tid];
            const float* wr = att_t_w + tid*ERNN;
            for (int k = 0; k < ERNN; ++k) s = fmaf(wr[k], ht[k], s);
            te[tid] = s;
        }
        __syncthreads();
        {
            float s = 0.f;
            for (int m = 0; m < 64; ++m) s = fmaf(att_s_w[m*ERNN + tid], te[m], s);
            u[tid] = s;
        }
        if (tid == 0) {
            float s = 0.f;
            for (int m = 0; m < 64; ++m) s = fmaf(te[m], att_s_b[m], s);
            msc[2] = s;
        }
        __syncthreads();
        {
            int slot = tid >> 1, half = tid & 1;
            float part = 0.f;
            if (slot < 127) {
                const float4* hs = (const float4*)(h + (size_t)(i*127 + slot)*256 + half*128);
                const float4* uu = (const float4*)(u + half*128);
                #pragma unroll 8
                for (int d = 0; d < 32; ++d) {
                    float4 a = hs[d], b = uu[d];
                    part = fmaf(a.x, b.x, part); part = fmaf(a.y, b.y, part);
                    part = fmaf(a.z, b.z, part); part = fmaf(a.w, b.w, part);
                }
            }
            part += __shfl_xor(part, 1);
            if (slot < 127 && (half == 0)) lg[slot] = (part + msc[2]) * TEMPSC;
            if (tid == 255) lg[127] = -1e30f;
        }
        __syncthreads();
        if (tid < 64) {
            float a = fmaxf(lg[tid], lg[tid+64]);
            for (int off = 32; off; off >>= 1) a = fmaxf(a, __shfl_xor(a, off));
            if (tid == 0) msc[0] = a;
        }
        __syncthreads();
        if (tid < 128) lg[tid] = (tid < 127) ? __expf(lg[tid] - msc[0]) : 0.f;
        else hnl[tid-128] = h_nn[i*128 + (tid-128)];
        __syncthreads();
        if (tid < 64) {
            float a = lg[tid] + lg[tid+64];
            for (int off = 32; off; off >>= 1) a += __shfl_xor(a, off);
            if (tid == 0) msc[1] = a;
        }
        __syncthreads();
        {
            float acc = 0.f;
            for (int slot = 0; slot < 127; ++slot)
                acc = fmaf(lg[slot], h[(size_t)(i*127 + slot)*256 + tid], acc);
            cat[tid] = ht[tid];
            cat[256 + tid] = acc / msc[1];
        }
        __syncthreads();
        if (tid < 64) {
            float p0 = nodes_prev[i*2], p1 = nodes_prev[i*2+1];
            xc[tid] = fmaxf(fmaf(n_enc_w[tid*2], p0, fmaf(n_enc_w[tid*2+1], p1, n_enc_b[tid])), 0.f);
        } else if (tid < 128) {
            int m = tid - 64;
            float s = n_attn_b[m];
            const float* wr = n_attn_w + m*512;
            for (int d = 0; d < 512; ++d) s = fmaf(wr[d], cat[d], s);
            xc[tid] = fmaxf(s, 0.f);
        }
        __syncthreads();
        #pragma unroll
        for (int rep = 0; rep < 2; ++rep) {
            int n = tid + rep*256;
            float s = n_bsum[n];
            for (int k = 0; k < 128; ++k) s = fmaf(n_wT[k*512 + n], xc[k], s);
            for (int k = 0; k < 128; ++k) s = fmaf(n_wT[(128+k)*512 + n], hnl[k], s);
            gl[n] = s;
        }
        __syncthreads();
        if (tid < 128) {
            float co = c_nn[i*128 + tid];
            float c2 = sigm(gl[128+tid])*co + sigm(gl[tid])*ftanh(gl[256+tid]);
            float h2 = sigm(gl[384+tid])*ftanh(c2);
            c_nn[i*128+tid] = c2;
            h_nn[i*128+tid] = h2;
            hnl[tid] = h2;
        }
        __syncthreads();
        if (tid < 5) {
            float s = out_b[tid];
            const float* wr = out_w + tid*128;
            for (int k = 0; k < 128; ++k) s = fmaf(wr[k], hnl[k], s);
            out_prev[i*5 + tid] = s;
        }
        return;
    }

    // ================= edge path (step t), 256 threads, R12 body =================
    if (!n_edge) return;
    unsigned short* Ah = (unsigned short*)smem;            // 8KB [kc(4)][row(128)][8]
    unsigned short* Bh = (unsigned short*)(smem + 8192);   // 4KB [kc(4)][col(64)][8]
    const int ebid = bid - NN;
    const int lane = tid & 63, wid = tid >> 6;
    const int wg = (ebid & 7)*256 + (ebid >> 3);   // XCD swizzle, bijective on 2048
    const int bm = wg >> 4, nt = wg & 15;          // 128 bm x 16 64-col tiles
    const bool sp = (bm < 127);
    const int rbase = bm * 128;
    const unsigned short* wHi = sp ? s_wHi : t_wHi;
    const float* bs = sp ? s_bs : t_bs;
    const int nt128 = nt >> 1, colh = (nt & 1)*64;

    auto stage = [&](int ks){
        const unsigned short* asrc = (ks < 2)
            ? xenc_t + ((size_t)bm*8  + ks*4     + wid)*1024
            : h_in   + ((size_t)bm*32 + (ks-2)*4 + wid)*1024;
        glds16(asrc + lane*8,       (char*)Ah + wid*2048);
        glds16(asrc + 512 + lane*8, (char*)Ah + wid*2048 + 1024);
        size_t wb = ((size_t)(nt128*40 + ks*4 + wid)*128 + colh)*8 + lane*8;
        glds16(wHi + wb, (char*)Bh + wid*1024);
    };
    stage(0);

    f32x4 acc[2][4];
    #pragma unroll
    for (int m = 0; m < 2; ++m)
        #pragma unroll
        for (int g = 0; g < 4; ++g)
            acc[m][g] = (f32x4){0.f,0.f,0.f,0.f};

    const int arow = wid*32 + (lane & 15);
    const int bcol = lane & 15;
    const int kg = lane >> 4;
    for (int ks = 0; ; ++ks) {
        __syncthreads();
        bf16x8 a[2], bb[4];
        #pragma unroll
        for (int m = 0; m < 2; ++m) a[m] = *(const bf16x8*)&Ah[(kg*128 + arow + m*16)*8];
        #pragma unroll
        for (int g = 0; g < 4; ++g) bb[g] = *(const bf16x8*)&Bh[(kg*64 + bcol + g*16)*8];
        #pragma unroll
        for (int m = 0; m < 2; ++m)
            #pragma unroll
            for (int g = 0; g < 4; ++g)
                acc[m][g] = __builtin_amdgcn_mfma_f32_16x16x32_bf16(a[m], bb[g], acc[m][g], 0, 0, 0);
        if (ks == 9) break;
        __syncthreads();
        stage(ks+1);
    }

    const int chl = lane & 15, q4 = (lane >> 4)*4;
    const int ch = nt*16 + chl;
    const int cbase = nt*64 + chl;
    const float b0 = bs[cbase], b1 = bs[cbase+16], b2 = bs[cbase+32], b3 = bs[cbase+48];
    #pragma unroll
    for (int m = 0; m < 2; ++m) {
        #pragma unroll
        for (int rg = 0; rg < 4; ++rg) {
            int lrow = wid*32 + m*16 + q4 + rg;
            int row = rbase + lrow;
            float gi = acc[m][0][rg] + b0;
            float gf = acc[m][1][rg] + b1;
            float gg = acc[m][2][rg] + b2;
            float go = acc[m][3][rg] + b3;
            size_t off = (size_t)row*256 + ch;
            float c_old = b2f(c_b[off]);
            float c2 = sigm(gf)*c_old + sigm(gi)*ftanh(gg);
            float h2 = sigm(go)*ftanh(c2);
            c_b[off] = f2b(c2);
            h_out[((size_t)(bm*32 + (ch>>3))*128 + lrow)*8 + (ch&7)] = f2b(h2);
            hf_out[off] = h2;
        }
    }
}

extern "C" void kernel_launch(void* const* d_in, const int* in_sizes, int n_in,
                              void* d_out, int out_size, void* d_ws, size_t ws_size,
                              hipStream_t stream)
{
    const float* nodes   = (const float*)d_in[0];
    const float* edges   = (const float*)d_in[1];
    const float* h_e0    = (const float*)d_in[2];
    const float* c_e0    = (const float*)d_in[3];
    const float* h_n0    = (const float*)d_in[4];
    const float* c_n0    = (const float*)d_in[5];
    const float* t_enc_w = (const float*)d_in[6];
    const float* t_enc_b = (const float*)d_in[7];
    const float* t_wih   = (const float*)d_in[8];
    const float* t_whh   = (const float*)d_in[9];
    const float* t_bih   = (const float*)d_in[10];
    const float* t_bhh   = (const float*)d_in[11];
    const float* s_enc_w = (const float*)d_in[12];
    const float* s_enc_b = (const float*)d_in[13];
    const float* s_wih   = (const float*)d_in[14];
    const float* s_whh   = (const float*)d_in[15];
    const float* s_bih   = (const float*)d_in[16];
    const float* s_bhh   = (const float*)d_in[17];
    const float* att_t_w = (const float*)d_in[18];
    const float* att_t_b = (const float*)d_in[19];
    const float* att_s_w = (const float*)d_in[20];
    const float* att_s_b = (const float*)d_in[21];
    const float* n_enc_w = (const float*)d_in[22];
    const float* n_enc_b = (const float*)d_in[23];
    const float* n_attn_w= (const float*)d_in[24];
    const float* n_attn_b= (const float*)d_in[25];
    const float* n_wih   = (const float*)d_in[26];
    const float* n_whh   = (const float*)d_in[27];
    const float* n_bih   = (const float*)d_in[28];
    const float* n_bhh   = (const float*)d_in[29];
    const float* out_w   = (const float*)d_in[30];
    const float* out_b   = (const float*)d_in[31];
    float* out = (float*)d_out;

    char* p = (char*)d_ws;
    float* h_nn  = (float*)p;            p += 128*128*4;
    float* c_nn  = (float*)p;            p += 128*128*4;
    float* s_bs  = (float*)p;            p += 1024*4;
    float* t_bs  = (float*)p;            p += 1024*4;
    float* n_wT  = (float*)p;            p += 256*512*4;
    float* n_bs  = (float*)p;            p += 512*4;
    float* hf_a  = (float*)p;            p += (size_t)16384*256*4;
    float* hf_b  = (float*)p;            p += (size_t)16384*256*4;
    unsigned short* c_b  = (unsigned short*)p;  p += (size_t)16384*256*2;
    unsigned short* h_a  = (unsigned short*)p;  p += (size_t)16384*256*2;
    unsigned short* h_b  = (unsigned short*)p;  p += (size_t)16384*256*2;
    unsigned short* xenc = (unsigned short*)p;  p += (size_t)TT*16384*64*2;
    unsigned short* s_wHi = (unsigned short*)p; p += 1024*320*2;
    unsigned short* t_wHi = (unsigned short*)p; p += 1024*320*2;

    int prep_blocks = (int)((PREP_TOT + 255) / 256);
    k_prep_all<<<prep_blocks, 256, 0, stream>>>(
        s_wih, s_whh, s_wHi, t_wih, t_whh, t_wHi,
        s_bih, s_bhh, s_bs, t_bih, t_bhh, t_bs,
        n_wih, n_whh, n_wT, n_bih, n_bhh, n_bs,
        h_n0, h_nn, c_n0, c_nn,
        h_e0, c_e0, h_a, c_b,
        edges, s_enc_w, s_enc_b, t_enc_w, t_enc_b, xenc);

    for (int t = 0; t < TT; ++t) {
        const unsigned short* h_in  = (t & 1) ? h_b : h_a;
        unsigned short*       h_out = (t & 1) ? h_a : h_b;
        float*       hf_out = (t & 1) ? hf_b : hf_a;
        const float* hf_prev= (t & 1) ? hf_a : hf_b;   // written by step t-1
        const float* nprev = (t > 0) ? nodes + (size_t)(t-1)*NN*2 : nodes;
        float* oprev = (t > 0) ? out + (size_t)(t-1)*NN*5 : out;
        k_fused<<<NN + 2048, 256, 0, stream>>>(xenc + (size_t)t*16384*64,
            h_in, h_out, hf_out, c_b,
            s_wHi, s_bs, t_wHi, t_bs,
            (t > 0) ? 1 : 0, 1,
            nprev, hf_prev, h_nn, c_nn, oprev,
            att_t_w, att_t_b, att_s_w, att_s_b, n_enc_w, n_enc_b,
            n_attn_w, n_attn_b, n_wT, n_bs, out_w, out_b);
    }
    // final node step (t = 19): reads hf written by edge step 19 (hf_b)
    k_fused<<<NN, 256, 0, stream>>>(xenc,
        h_a, h_b, hf_a, c_b,
        s_wHi, s_bs, t_wHi, t_bs,
        1, 0,
        nodes + (size_t)19*NN*2, hf_b, h_nn, c_nn, out + (size_t)19*NN*5,
        att_t_w, att_t_b, att_s_w, att_s_b, n_enc_w, n_enc_b,
        n_attn_w, n_attn_b, n_wT, n_bs, out_w, out_b);
}

// Round 21
// 666.625 us; speedup vs baseline: 51.2889x; 1.8395x over previous
//
#include <hip/hip_runtime.h>
#include <cmath>

#define NN 128
#define TT 20
#define ERNN 256
#define TEMPSC 15.875f /* (N-1)/sqrt(ATT) = 127/8 */

typedef __attribute__((ext_vector_type(8))) short bf16x8;
typedef __attribute__((ext_vector_type(4))) float f32x4;

__device__ __forceinline__ float sigm(float x){ return 1.f/(1.f+__expf(-x)); }
__device__ __forceinline__ float ftanh(float x){ float e = __expf(2.f*x); return 1.f - 2.f/(e + 1.f); }
__device__ __forceinline__ float b2f(unsigned short u){ union{unsigned int i; float f;} v; v.i = ((unsigned int)u)<<16; return v.f; }
__device__ __forceinline__ unsigned short f2b(float x){ union{float f; unsigned int u;} v; v.f = x; unsigned int r = v.u + 0x7fffu + ((v.u>>16)&1u); return (unsigned short)(r>>16); }

typedef __attribute__((address_space(3))) unsigned int lds_u32;
typedef __attribute__((address_space(1))) unsigned int glb_u32;
__device__ __forceinline__ void glds16(const void* g, void* l){
    __builtin_amdgcn_global_load_lds((const glb_u32*)g, (lds_u32*)l, 16, 0, 0);
}

// chunked h: [tile=r>>7][kc=d>>3 (32)][row=r&127][q=d&7]
__device__ __forceinline__ size_t hoff(int r, int d){
    return ((size_t)((r>>7)*32 + (d>>3))*128 + (r&127))*8 + (d&7);
}

// ---- one mega-prep kernel (xenc removed: encoder now lives in k_fused) ----
#define R_W2    (2*1024*320)
#define R_EB    2048
#define R_NWT   131072
#define R_NBS   512
#define R_HNN   16384
#define R_CNN   16384
#define R_INIT  (16384*32)
#define PREP_TOT (R_W2 + R_EB + R_NWT + R_NBS + R_HNN + R_CNN + R_INIT)

__global__ void k_prep_all(
    const float* __restrict__ s_wih, const float* __restrict__ s_whh, unsigned short* __restrict__ s_wHi,
    const float* __restrict__ t_wih, const float* __restrict__ t_whh, unsigned short* __restrict__ t_wHi,
    const float* __restrict__ s_bih, const float* __restrict__ s_bhh, float* __restrict__ s_bs,
    const float* __restrict__ t_bih, const float* __restrict__ t_bhh, float* __restrict__ t_bs,
    const float* __restrict__ n_wih, const float* __restrict__ n_whh, float* __restrict__ n_wT,
    const float* __restrict__ n_bih, const float* __restrict__ n_bhh, float* __restrict__ n_bs,
    const float* __restrict__ h_n0, float* __restrict__ h_nn,
    const float* __restrict__ c_n0, float* __restrict__ c_nn,
    const float* __restrict__ h_e0, const float* __restrict__ c_e0,
    unsigned short* __restrict__ hHi, unsigned short* __restrict__ c_b)
{
    size_t i = (size_t)blockIdx.x*256 + threadIdx.x;
    if (i < R_W2) {
        int idx = (int)i;
        int which = idx >= 1024*320;
        if (which) idx -= 1024*320;
        const float* wih = which ? t_wih : s_wih;
        const float* whh = which ? t_whh : s_whh;
        unsigned short* wHi = which ? t_wHi : s_wHi;
        int c = idx / 320, k = idx - c*320;
        int ch = ((c>>6)<<4) + (c&15), g = (c>>4)&3;
        int r = g*256 + ch;
        float v = (k < 64) ? wih[r*64 + k] : whh[r*256 + (k-64)];
        size_t dst = ((size_t)((c>>7)*40 + (k>>3))*128 + (c&127))*8 + (k&7);
        wHi[dst] = f2b(v);
        return;
    }
    i -= R_W2;
    if (i < R_EB) {
        int c = (int)i, which = c >= 1024;
        if (which) c -= 1024;
        const float* bih = which ? t_bih : s_bih;
        const float* bhh = which ? t_bhh : s_bhh;
        float* bs = which ? t_bs : s_bs;
        int ch = ((c>>6)<<4)+(c&15), g=(c>>4)&3;
        int r = g*256+ch;
        bs[c] = bih[r] + bhh[r];
        return;
    }
    i -= R_EB;
    if (i < R_NWT) {
        int j = (int)i;
        if (j < 65536) { int r = j >> 7, c = j & 127; n_wT[c*512 + r] = n_wih[j]; }
        else { j -= 65536; int r = j >> 7, c = j & 127; n_wT[(128 + c)*512 + r] = n_whh[j]; }
        return;
    }
    i -= R_NWT;
    if (i < R_NBS) { n_bs[i] = n_bih[i] + n_bhh[i]; return; }
    i -= R_NBS;
    if (i < R_HNN) { h_nn[i] = h_n0[i]; return; }
    i -= R_HNN;
    if (i < R_CNN) { c_nn[i] = c_n0[i]; return; }
    i -= R_CNN;
    if (i < R_INIT) {
        int g = (int)i;
        int d8 = g & 31, r = g >> 5;
        int row_ij;
        if (r < 16256){ int ii = r/127, jj = r - ii*127; row_ij = ii*NN + jj + (jj>=ii ? 1:0); }
        else          { row_ij = (r - 16256)*(NN+1); }
        const float* hs = h_e0 + (size_t)row_ij*ERNN + d8*8;
        const float* cs = c_e0 + (size_t)row_ij*ERNN + d8*8;
        bf16x8 hb, cb;
        #pragma unroll
        for (int q = 0; q < 8; ++q){ hb[q] = (short)f2b(hs[q]); cb[q] = (short)f2b(cs[q]); }
        *(bf16x8*)&hHi[hoff(r, d8*8)] = hb;
        *(bf16x8*)&c_b[(size_t)r*ERNN + d8*8] = cb;
        return;
    }
}

// One pipelined edge K-step: counted vmcnt(NW) + raw barriers; prefetch depth 2.
#define ESTEP(KS, NW) do { \
    asm volatile("s_waitcnt vmcnt(" #NW ")" ::: "memory"); \
    __builtin_amdgcn_s_barrier(); \
    __builtin_amdgcn_sched_barrier(0); \
    bf16x8 a0 = *(const bf16x8*)&Ah[(KS)&1][(kg*128 + arow)*8]; \
    bf16x8 a1 = *(const bf16x8*)&Ah[(KS)&1][(kg*128 + arow + 16)*8]; \
    bf16x8 b0 = *(const bf16x8*)&Bh[(KS)&1][(kg*128 + bcol)*8]; \
    bf16x8 b1 = *(const bf16x8*)&Bh[(KS)&1][(kg*128 + bcol + 16)*8]; \
    bf16x8 b2 = *(const bf16x8*)&Bh[(KS)&1][(kg*128 + bcol + 32)*8]; \
    bf16x8 b3 = *(const bf16x8*)&Bh[(KS)&1][(kg*128 + bcol + 48)*8]; \
    asm volatile("s_waitcnt lgkmcnt(0)" ::: "memory"); \
    __builtin_amdgcn_sched_barrier(0); \
    __builtin_amdgcn_s_barrier(); \
    if ((KS) + 2 <= 9) stage((KS)+2, (KS)&1); \
    acc[0][0] = __builtin_amdgcn_mfma_f32_16x16x32_bf16(a0, b0, acc[0][0],0,0,0); \
    acc[0][1] = __builtin_amdgcn_mfma_f32_16x16x32_bf16(a0, b1, acc[0][1],0,0,0); \
    acc[0][2] = __builtin_amdgcn_mfma_f32_16x16x32_bf16(a0, b2, acc[0][2],0,0,0); \
    acc[0][3] = __builtin_amdgcn_mfma_f32_16x16x32_bf16(a0, b3, acc[0][3],0,0,0); \
    acc[1][0] = __builtin_amdgcn_mfma_f32_16x16x32_bf16(a1, b0, acc[1][0],0,0,0); \
    acc[1][1] = __builtin_amdgcn_mfma_f32_16x16x32_bf16(a1, b1, acc[1][1],0,0,0); \
    acc[1][2] = __builtin_amdgcn_mfma_f32_16x16x32_bf16(a1, b2, acc[1][2],0,0,0); \
    acc[1][3] = __builtin_amdgcn_mfma_f32_16x16x32_bf16(a1, b3, acc[1][3],0,0,0); \
} while(0)

// Fused per-step (R18 structure): blocks [0,128) = node t-1; [128,1152) = edge t.
// Edge: encoder computed in-block into Ah[0]/Ah[1] (ks 0,1); B-only prologue
// stages; ledger: ESTEP(0)=vmcnt(1), steady=2, final=0.
__global__ __launch_bounds__(512) void k_fused(
    const float* __restrict__ edges_t,
    const unsigned short* __restrict__ h_in, unsigned short* __restrict__ h_out,
    unsigned short* __restrict__ hl_out, unsigned short* __restrict__ c_b,
    const unsigned short* __restrict__ s_wHi, const float* __restrict__ s_bs,
    const unsigned short* __restrict__ t_wHi, const float* __restrict__ t_bs,
    const float* __restrict__ s_enc_w, const float* __restrict__ s_enc_b,
    const float* __restrict__ t_enc_w, const float* __restrict__ t_enc_b,
    int has_node, int n_edge,
    const float* __restrict__ nodes_prev, const unsigned short* __restrict__ hl_prev,
    float* __restrict__ h_nn, float* __restrict__ c_nn, float* __restrict__ out_prev,
    const float* __restrict__ att_t_w, const float* __restrict__ att_t_b,
    const float* __restrict__ att_s_w, const float* __restrict__ att_s_b,
    const float* __restrict__ n_enc_w, const float* __restrict__ n_enc_b,
    const float* __restrict__ n_attn_w, const float* __restrict__ n_attn_b,
    const float* __restrict__ n_wT, const float* __restrict__ n_bsum,
    const float* __restrict__ out_w, const float* __restrict__ out_b)
{
    __shared__ __align__(16) char smem[32768];
    const int bid = blockIdx.x, tid = threadIdx.x;

    if (bid < NN) {
        // ================= node path (step t-1), 512 threads =================
        if (!has_node) return;
        const int i = bid;
        float* sm  = (float*)smem;
        float* ht  = sm;           float* te  = sm + 256;
        float* u   = sm + 320;     float* lg  = sm + 576;
        float* cat = sm + 704;     float* xc  = sm + 1216;
        float* hnl = sm + 1344;    float* gl  = sm + 1472;
        float* pws = sm + 1984;    float* msc = sm + 4032;

        if (tid < 256) ht[tid] = b2f(hl_prev[(size_t)(16256 + i)*256 + tid]);
        __syncthreads();
        if (tid < 256) {            // te: 4 threads per row m
            int m = tid >> 2, q = tid & 3;
            float s = 0.f;
            const float* wr = att_t_w + m*ERNN + q*64;
            const float* hh = ht + q*64;
            #pragma unroll 8
            for (int k = 0; k < 64; ++k) s = fmaf(wr[k], hh[k], s);
            s += __shfl_xor(s, 1);
            s += __shfl_xor(s, 2);
            if (q == 0) te[m] = s + att_t_b[m];
        }
        __syncthreads();
        if (tid < 256) {            // u = att_s_w^T te
            float s = 0.f;
            for (int m = 0; m < 64; ++m) s = fmaf(att_s_w[m*ERNN + tid], te[m], s);
            u[tid] = s;
        }
        if (tid == 320) {
            float s = 0.f;
            for (int m = 0; m < 64; ++m) s = fmaf(te[m], att_s_b[m], s);
            msc[2] = s;
        }
        __syncthreads();
        {                           // logits: 4 threads per slot
            int slot = tid >> 2, q = tid & 3;
            float part = 0.f;
            if (slot < 127) {
                const unsigned short* hs = hl_prev + (size_t)(i*127 + slot)*256 + q*64;
                const float* uu = u + q*64;
                #pragma unroll
                for (int d8 = 0; d8 < 8; ++d8) {
                    bf16x8 v = *(const bf16x8*)(hs + d8*8);
                    #pragma unroll
                    for (int j = 0; j < 8; ++j)
                        part = fmaf(uu[d8*8 + j], b2f((unsigned short)v[j]), part);
                }
            }
            part += __shfl_xor(part, 1);
            part += __shfl_xor(part, 2);
            if (slot < 127 && q == 0) lg[slot] = (part + msc[2]) * TEMPSC;
            if (tid == 511) lg[127] = -1e30f;
        }
        __syncthreads();
        if (tid < 64) {
            float a = fmaxf(lg[tid], lg[tid+64]);
            for (int off = 32; off; off >>= 1) a = fmaxf(a, __shfl_xor(a, off));
            if (tid == 0) msc[0] = a;
        }
        __syncthreads();
        if (tid < 128) lg[tid] = (tid < 127) ? __expf(lg[tid] - msc[0]) : 0.f;
        __syncthreads();
        if (tid < 64) {
            float a = lg[tid] + lg[tid+64];
            for (int off = 32; off; off >>= 1) a += __shfl_xor(a, off);
            if (tid == 0) msc[1] = a;
        }
        __syncthreads();
        {                           // weighted sum: 8 waves x 16 slots
            int w = tid >> 6, lane = tid & 63;
            float a0 = 0.f, a1 = 0.f, a2 = 0.f, a3 = 0.f;
            #pragma unroll 4
            for (int s = w*16; s < w*16 + 16; ++s) {
                int srow = (s < 127) ? s : 0;
                float wgt = lg[s];
                const unsigned short* hs = hl_prev + (size_t)(i*127 + srow)*256 + lane*4;
                ushort4 v = *(const ushort4*)hs;
                a0 = fmaf(wgt, b2f(v.x), a0);
                a1 = fmaf(wgt, b2f(v.y), a1);
                a2 = fmaf(wgt, b2f(v.z), a2);
                a3 = fmaf(wgt, b2f(v.w), a3);
            }
            pws[w*256 + lane*4+0] = a0; pws[w*256 + lane*4+1] = a1;
            pws[w*256 + lane*4+2] = a2; pws[w*256 + lane*4+3] = a3;
        }
        if (tid >= 256 && tid < 384) hnl[tid-256] = h_nn[i*128 + (tid-256)];
        __syncthreads();
        if (tid < 256) {
            float s = 0.f;
            #pragma unroll
            for (int w = 0; w < 8; ++w) s += pws[w*256 + tid];
            cat[256 + tid] = s / msc[1];
            cat[tid] = ht[tid];
        }
        __syncthreads();
        if (tid < 64) {             // enc -> xc[0:64]
            float p0 = nodes_prev[i*2], p1 = nodes_prev[i*2+1];
            xc[tid] = fmaxf(fmaf(n_enc_w[tid*2], p0, fmaf(n_enc_w[tid*2+1], p1, n_enc_b[tid])), 0.f);
        }
        if (tid >= 256) {           // h_emb: 4 threads per row m -> xc[64:128]
            int t2 = tid - 256;
            int m = t2 >> 2, q = t2 & 3;
            float s = 0.f;
            const float* wr = n_attn_w + m*512 + q*128;
            const float* cc = cat + q*128;
            #pragma unroll 8
            for (int d = 0; d < 128; ++d) s = fmaf(wr[d], cc[d], s);
            s += __shfl_xor(s, 1);
            s += __shfl_xor(s, 2);
            if (q == 0) xc[64 + m] = fmaxf(s + n_attn_b[m], 0.f);
        }
        __syncthreads();
        {                           // node LSTM gates: one thread per gate-channel
            int n = tid;
            float s = n_bsum[n];
            for (int k = 0; k < 128; ++k) s = fmaf(n_wT[k*512 + n], xc[k], s);
            for (int k = 0; k < 128; ++k) s = fmaf(n_wT[(128+k)*512 + n], hnl[k], s);
            gl[n] = s;
        }
        __syncthreads();
        if (tid < 128) {
            float co = c_nn[i*128 + tid];
            float c2 = sigm(gl[128+tid])*co + sigm(gl[tid])*ftanh(gl[256+tid]);
            float h2 = sigm(gl[384+tid])*ftanh(c2);
            c_nn[i*128+tid] = c2;
            h_nn[i*128+tid] = h2;
            hnl[tid] = h2;
        }
        __syncthreads();
        if (tid < 5) {
            float s = out_b[tid];
            const float* wr = out_w + tid*128;
            for (int k = 0; k < 128; ++k) s = fmaf(wr[k], hnl[k], s);
            out_prev[i*5 + tid] = s;
        }
        return;
    }

    // ================= edge path (step t), 512 threads, dbuf pipeline ====
    if (!n_edge) return;
    unsigned short (*Ah)[4096] = (unsigned short(*)[4096])smem;            // 2x8KB
    unsigned short (*Bh)[4096] = (unsigned short(*)[4096])(smem + 16384);  // 2x8KB
    const int ebid = bid - NN;
    const int lane = tid & 63, wid = tid >> 6;
    const int wg = (ebid & 7)*128 + (ebid >> 3);   // XCD swizzle, bijective on 1024
    const int bm = wg >> 3, ntp = wg & 7;          // 128 bm x 8 col-pairs
    const bool sp = (bm < 127);
    const int rbase = bm * 128;
    const unsigned short* wHi = sp ? s_wHi : t_wHi;
    const float* bs = sp ? s_bs : t_bs;
    const float* enc_w = sp ? s_enc_w : t_enc_w;
    const float* enc_b = sp ? s_enc_b : t_enc_b;
    const int wr = wid & 3, wc = wid >> 2;         // row-group, col-half
    const int nt = ntp*2 + wc;                     // [0,16) 64-col group

    // B-only stage for prologue ks<2; full stage for ks>=2 (1 A + 1 B glds/wave)
    auto stageB = [&](int ks, int b){
        int kc = wid >> 1, half = wid & 1;
        size_t wb = ((size_t)(ntp*40 + ks*4 + kc)*128 + half*64)*8;
        glds16(wHi + wb + lane*8, (char*)&Bh[b][0] + wid*1024);
    };
    auto stage = [&](int ks, int b){
        int kc = wid >> 1, half = wid & 1;
        const unsigned short* asrc =
            h_in + ((size_t)bm*32 + (ks-2)*4 + kc)*1024 + half*512;
        glds16(asrc + lane*8, (char*)&Ah[b][0] + wid*1024);
        size_t wb = ((size_t)(ntp*40 + ks*4 + kc)*128 + half*64)*8;
        glds16(wHi + wb + lane*8, (char*)&Bh[b][0] + wid*1024);
    };

    // issue B prologue first so loads fly under the encoder compute
    stageB(0, 0);
    stageB(1, 1);

    // encoder: X cols 0..63 for this bm's 128 rows, into Ah[0] (ks0) / Ah[1] (ks1).
    // chunk c in [0,1024): row=c&127, kcg=c>>7 in [0,8); buf=kcg>>2, lkc=kcg&3.
    #pragma unroll
    for (int rep = 0; rep < 2; ++rep) {
        int c = rep*512 + tid;
        int row = c & 127, kcg = c >> 7;
        int r = rbase + row;
        int row_ij;
        if (sp) { int ii = r/127, jj = r - ii*127; row_ij = ii*NN + jj + (jj>=ii ? 1:0); }
        else    { row_ij = (r - 16256)*(NN+1); }
        float e0 = edges_t[row_ij*2], e1 = edges_t[row_ij*2+1];
        bf16x8 ph;
        #pragma unroll
        for (int q = 0; q < 8; ++q) {
            int m = kcg*8 + q;
            ph[q] = (short)f2b(fmaxf(fmaf(enc_w[m*2], e0, fmaf(enc_w[m*2+1], e1, enc_b[m])), 0.f));
        }
        *(bf16x8*)&Ah[kcg>>2][((kcg&3)*128 + row)*8] = ph;
    }
    asm volatile("s_waitcnt lgkmcnt(0)" ::: "memory");   // enc ds_writes drained

    f32x4 acc[2][4];
    #pragma unroll
    for (int m = 0; m < 2; ++m)
        #pragma unroll
        for (int g = 0; g < 4; ++g)
            acc[m][g] = (f32x4){0.f,0.f,0.f,0.f};

    const int arow = wr*32 + (lane & 15);
    const int bcol = wc*64 + (lane & 15);
    const int kg = lane >> 4;

    // ledger: prologue outstanding = 2 (B0,B1). ESTEP(0) waits 1 (B0 landed);
    // each steady stage adds 2 (A+B); steady wait 2; final drain 0.
    ESTEP(0, 1);
    ESTEP(1, 2);
    ESTEP(2, 2);
    ESTEP(3, 2);
    ESTEP(4, 2);
    ESTEP(5, 2);
    ESTEP(6, 2);
    ESTEP(7, 2);
    ESTEP(8, 2);
    ESTEP(9, 0);

    const int chl = lane & 15, q4 = (lane >> 4)*4;
    const int ch = nt*16 + chl;
    const int cbase = nt*64 + chl;
    const float b0 = bs[cbase], b1 = bs[cbase+16], b2 = bs[cbase+32], b3 = bs[cbase+48];
    #pragma unroll
    for (int m = 0; m < 2; ++m) {
        #pragma unroll
        for (int rg = 0; rg < 4; ++rg) {
            int lrow = wr*32 + m*16 + q4 + rg;
            int row = rbase + lrow;
            float gi = acc[m][0][rg] + b0;
            float gf = acc[m][1][rg] + b1;
            float gg = acc[m][2][rg] + b2;
            float go = acc[m][3][rg] + b3;
            size_t off = (size_t)row*256 + ch;
            float c_old = b2f(c_b[off]);
            float c2 = sigm(gf)*c_old + sigm(gi)*ftanh(gg);
            float h2 = sigm(go)*ftanh(c2);
            c_b[off] = f2b(c2);
            unsigned short hb = f2b(h2);
            h_out[((size_t)(bm*32 + (ch>>3))*128 + lrow)*8 + (ch&7)] = hb;
            hl_out[off] = hb;
        }
    }
}

extern "C" void kernel_launch(void* const* d_in, const int* in_sizes, int n_in,
                              void* d_out, int out_size, void* d_ws, size_t ws_size,
                              hipStream_t stream)
{
    const float* nodes   = (const float*)d_in[0];
    const float* edges   = (const float*)d_in[1];
    const float* h_e0    = (const float*)d_in[2];
    const float* c_e0    = (const float*)d_in[3];
    const float* h_n0    = (const float*)d_in[4];
    const float* c_n0    = (const float*)d_in[5];
    const float* t_enc_w = (const float*)d_in[6];
    const float* t_enc_b = (const float*)d_in[7];
    const float* t_wih   = (const float*)d_in[8];
    const float* t_whh   = (const float*)d_in[9];
    const float* t_bih   = (const float*)d_in[10];
    const float* t_bhh   = (const float*)d_in[11];
    const float* s_enc_w = (const float*)d_in[12];
    const float* s_enc_b = (const float*)d_in[13];
    const float* s_wih   = (const float*)d_in[14];
    const float* s_whh   = (const float*)d_in[15];
    const float* s_bih   = (const float*)d_in[16];
    const float* s_bhh   = (const float*)d_in[17];
    const float* att_t_w = (const float*)d_in[18];
    const float* att_t_b = (const float*)d_in[19];
    const float* att_s_w = (const float*)d_in[20];
    const float* att_s_b = (const float*)d_in[21];
    const float* n_enc_w = (const float*)d_in[22];
    const float* n_enc_b = (const float*)d_in[23];
    const float* n_attn_w= (const float*)d_in[24];
    const float* n_attn_b= (const float*)d_in[25];
    const float* n_wih   = (const float*)d_in[26];
    const float* n_whh   = (const float*)d_in[27];
    const float* n_bih   = (const float*)d_in[28];
    const float* n_bhh   = (const float*)d_in[29];
    const float* out_w   = (const float*)d_in[30];
    const float* out_b   = (const float*)d_in[31];
    float* out = (float*)d_out;

    char* p = (char*)d_ws;
    float* h_nn  = (float*)p;            p += 128*128*4;
    float* c_nn  = (float*)p;            p += 128*128*4;
    float* s_bs  = (float*)p;            p += 1024*4;
    float* t_bs  = (float*)p;            p += 1024*4;
    float* n_wT  = (float*)p;            p += 256*512*4;
    float* n_bs  = (float*)p;            p += 512*4;
    unsigned short* c_b  = (unsigned short*)p;  p += (size_t)16384*256*2;
    unsigned short* h_a  = (unsigned short*)p;  p += (size_t)16384*256*2;
    unsigned short* h_b  = (unsigned short*)p;  p += (size_t)16384*256*2;
    unsigned short* hl_a = (unsigned short*)p;  p += (size_t)16384*256*2;
    unsigned short* hl_b = (unsigned short*)p;  p += (size_t)16384*256*2;
    unsigned short* s_wHi = (unsigned short*)p; p += 1024*320*2;
    unsigned short* t_wHi = (unsigned short*)p; p += 1024*320*2;

    int prep_blocks = (int)((PREP_TOT + 255) / 256);
    k_prep_all<<<prep_blocks, 256, 0, stream>>>(
        s_wih, s_whh, s_wHi, t_wih, t_whh, t_wHi,
        s_bih, s_bhh, s_bs, t_bih, t_bhh, t_bs,
        n_wih, n_whh, n_wT, n_bih, n_bhh, n_bs,
        h_n0, h_nn, c_n0, c_nn,
        h_e0, c_e0, h_a, c_b);

    for (int t = 0; t < TT; ++t) {
        const unsigned short* h_in  = (t & 1) ? h_b : h_a;
        unsigned short*       h_out = (t & 1) ? h_a : h_b;
        unsigned short*       hl_out= (t & 1) ? hl_b : hl_a;
        const unsigned short* hl_prev=(t & 1) ? hl_a : hl_b;   // written by step t-1
        const float* nprev = (t > 0) ? nodes + (size_t)(t-1)*NN*2 : nodes;
        float* oprev = (t > 0) ? out + (size_t)(t-1)*NN*5 : out;
        k_fused<<<NN + 1024, 512, 0, stream>>>(edges + (size_t)t*16384*2,
            h_in, h_out, hl_out, c_b,
            s_wHi, s_bs, t_wHi, t_bs,
            s_enc_w, s_enc_b, t_enc_w, t_enc_b,
            (t > 0) ? 1 : 0, 1024,
            nprev, hl_prev, h_nn, c_nn, oprev,
            att_t_w, att_t_b, att_s_w, att_s_b, n_enc_w, n_enc_b,
            n_attn_w, n_attn_b, n_wT, n_bs, out_w, out_b);
    }
    // final node step (t = 19): reads hl written by edge step 19 (hl_b)
    k_fused<<<NN, 512, 0, stream>>>(edges,
        h_a, h_b, hl_a, c_b,
        s_wHi, s_bs, t_wHi, t_bs,
        s_enc_w, s_enc_b, t_enc_w, t_enc_b,
        1, 0,
        nodes + (size_t)19*NN*2, hl_b, h_nn, c_nn, out + (size_t)19*NN*5,
        att_t_w, att_t_b, att_s_w, att_s_b, n_enc_w, n_enc_b,
        n_attn_w, n_attn_b, n_wT, n_bs, out_w, out_b);
}

// Round 22
// 590.512 us; speedup vs baseline: 57.8997x; 1.1289x over previous
//
#include <hip/hip_runtime.h>
#include <cmath>

#define NN 128
#define TT 20
#define ERNN 256
#define TEMPSC 15.875f /* (N-1)/sqrt(ATT) = 127/8 */

typedef __attribute__((ext_vector_type(8))) short bf16x8;
typedef __attribute__((ext_vector_type(4))) float f32x4;

__device__ __forceinline__ float sigm(float x){ return 1.f/(1.f+__expf(-x)); }
__device__ __forceinline__ float ftanh(float x){ float e = __expf(2.f*x); return 1.f - 2.f/(e + 1.f); }
__device__ __forceinline__ float b2f(unsigned short u){ union{unsigned int i; float f;} v; v.i = ((unsigned int)u)<<16; return v.f; }
__device__ __forceinline__ unsigned short f2b(float x){ union{float f; unsigned int u;} v; v.f = x; unsigned int r = v.u + 0x7fffu + ((v.u>>16)&1u); return (unsigned short)(r>>16); }

typedef __attribute__((address_space(3))) unsigned int lds_u32;
typedef __attribute__((address_space(1))) unsigned int glb_u32;
__device__ __forceinline__ void glds16(const void* g, void* l){
    __builtin_amdgcn_global_load_lds((const glb_u32*)g, (lds_u32*)l, 16, 0, 0);
}

// chunked h: [tile=r>>7][kc=d>>3 (32)][row=r&127][q=d&7]
__device__ __forceinline__ size_t hoff(int r, int d){
    return ((size_t)((r>>7)*32 + (d>>3))*128 + (r&127))*8 + (d&7);
}

// ---- one mega-prep kernel ----
#define R_W2    (2*1024*320)
#define R_EB    2048
#define R_NWT   131072
#define R_NBS   512
#define R_HNN   16384
#define R_CNN   16384
#define R_INIT  (16384*32)
#define R_XENC  ((size_t)TT*16384*8)
#define PREP_TOT (R_W2 + R_EB + R_NWT + R_NBS + R_HNN + R_CNN + R_INIT + R_XENC)

__global__ void k_prep_all(
    const float* __restrict__ s_wih, const float* __restrict__ s_whh, unsigned short* __restrict__ s_wHi,
    const float* __restrict__ t_wih, const float* __restrict__ t_whh, unsigned short* __restrict__ t_wHi,
    const float* __restrict__ s_bih, const float* __restrict__ s_bhh, float* __restrict__ s_bs,
    const float* __restrict__ t_bih, const float* __restrict__ t_bhh, float* __restrict__ t_bs,
    const float* __restrict__ n_wih, const float* __restrict__ n_whh, float* __restrict__ n_wT,
    const float* __restrict__ n_bih, const float* __restrict__ n_bhh, float* __restrict__ n_bs,
    const float* __restrict__ h_n0, float* __restrict__ h_nn,
    const float* __restrict__ c_n0, float* __restrict__ c_nn,
    const float* __restrict__ h_e0, const float* __restrict__ c_e0,
    unsigned short* __restrict__ hHi, unsigned short* __restrict__ c_b,
    const float* __restrict__ edges,
    const float* __restrict__ s_enc_w, const float* __restrict__ s_enc_b,
    const float* __restrict__ t_enc_w, const float* __restrict__ t_enc_b,
    unsigned short* __restrict__ xe)
{
    size_t i = (size_t)blockIdx.x*256 + threadIdx.x;
    if (i < R_W2) {
        int idx = (int)i;
        int which = idx >= 1024*320;
        if (which) idx -= 1024*320;
        const float* wih = which ? t_wih : s_wih;
        const float* whh = which ? t_whh : s_whh;
        unsigned short* wHi = which ? t_wHi : s_wHi;
        int c = idx / 320, k = idx - c*320;
        int ch = ((c>>6)<<4) + (c&15), g = (c>>4)&3;
        int r = g*256 + ch;
        float v = (k < 64) ? wih[r*64 + k] : whh[r*256 + (k-64)];
        size_t dst = ((size_t)((c>>7)*40 + (k>>3))*128 + (c&127))*8 + (k&7);
        wHi[dst] = f2b(v);
        return;
    }
    i -= R_W2;
    if (i < R_EB) {
        int c = (int)i, which = c >= 1024;
        if (which) c -= 1024;
        const float* bih = which ? t_bih : s_bih;
        const float* bhh = which ? t_bhh : s_bhh;
        float* bs = which ? t_bs : s_bs;
        int ch = ((c>>6)<<4)+(c&15), g=(c>>4)&3;
        int r = g*256+ch;
        bs[c] = bih[r] + bhh[r];
        return;
    }
    i -= R_EB;
    if (i < R_NWT) {
        int j = (int)i;
        if (j < 65536) { int r = j >> 7, c = j & 127; n_wT[c*512 + r] = n_wih[j]; }
        else { j -= 65536; int r = j >> 7, c = j & 127; n_wT[(128 + c)*512 + r] = n_whh[j]; }
        return;
    }
    i -= R_NWT;
    if (i < R_NBS) { n_bs[i] = n_bih[i] + n_bhh[i]; return; }
    i -= R_NBS;
    if (i < R_HNN) { h_nn[i] = h_n0[i]; return; }
    i -= R_HNN;
    if (i < R_CNN) { c_nn[i] = c_n0[i]; return; }
    i -= R_CNN;
    if (i < R_INIT) {
        int g = (int)i;
        int d8 = g & 31, r = g >> 5;
        int row_ij;
        if (r < 16256){ int ii = r/127, jj = r - ii*127; row_ij = ii*NN + jj + (jj>=ii ? 1:0); }
        else          { row_ij = (r - 16256)*(NN+1); }
        const float* hs = h_e0 + (size_t)row_ij*ERNN + d8*8;
        const float* cs = c_e0 + (size_t)row_ij*ERNN + d8*8;
        bf16x8 hb, cb;
        #pragma unroll
        for (int q = 0; q < 8; ++q){ hb[q] = (short)f2b(hs[q]); cb[q] = (short)f2b(cs[q]); }
        *(bf16x8*)&hHi[hoff(r, d8*8)] = hb;
        *(bf16x8*)&c_b[(size_t)r*ERNN + d8*8] = cb;
        return;
    }
    i -= R_INIT;
    if (i < R_XENC) {
        size_t g = i;
        int row = (int)(g & 127);
        size_t rest = g >> 7;
        int kc = (int)(rest & 7);
        int tile = (int)((rest >> 3) & 127);
        int t = (int)(rest >> 10);
        int r = tile*128 + row;
        bool sp = (r < 16256);
        int row_ij;
        if (sp) { int ii = r/127, jj = r - ii*127; row_ij = ii*NN + jj + (jj>=ii ? 1:0); }
        else    { row_ij = (r - 16256)*(NN+1); }
        const float* w = sp ? s_enc_w : t_enc_w;
        const float* b = sp ? s_enc_b : t_enc_b;
        float e0 = edges[((size_t)t*16384 + row_ij)*2];
        float e1 = edges[((size_t)t*16384 + row_ij)*2 + 1];
        bf16x8 v8;
        #pragma unroll
        for (int q = 0; q < 8; ++q) {
            int m = kc*8 + q;
            v8[q] = (short)f2b(fmaxf(fmaf(w[m*2], e0, fmaf(w[m*2+1], e1, b[m])), 0.f));
        }
        *(bf16x8*)&xe[g*8] = v8;
    }
}

// One pipelined edge K-step: counted vmcnt(NW) + raw barriers; prefetch depth 2.
#define ESTEP(KS, NW) do { \
    asm volatile("s_waitcnt vmcnt(" #NW ")" ::: "memory"); \
    __builtin_amdgcn_s_barrier(); \
    __builtin_amdgcn_sched_barrier(0); \
    bf16x8 a0 = *(const bf16x8*)&Ah[(KS)&1][(kg*128 + arow)*8]; \
    bf16x8 a1 = *(const bf16x8*)&Ah[(KS)&1][(kg*128 + arow + 16)*8]; \
    bf16x8 b0 = *(const bf16x8*)&Bh[(KS)&1][(kg*128 + bcol)*8]; \
    bf16x8 b1 = *(const bf16x8*)&Bh[(KS)&1][(kg*128 + bcol + 16)*8]; \
    bf16x8 b2 = *(const bf16x8*)&Bh[(KS)&1][(kg*128 + bcol + 32)*8]; \
    bf16x8 b3 = *(const bf16x8*)&Bh[(KS)&1][(kg*128 + bcol + 48)*8]; \
    asm volatile("s_waitcnt lgkmcnt(0)" ::: "memory"); \
    __builtin_amdgcn_sched_barrier(0); \
    __builtin_amdgcn_s_barrier(); \
    if ((KS) + 2 <= 9) stage((KS)+2, (KS)&1); \
    acc[0][0] = __builtin_amdgcn_mfma_f32_16x16x32_bf16(a0, b0, acc[0][0],0,0,0); \
    acc[0][1] = __builtin_amdgcn_mfma_f32_16x16x32_bf16(a0, b1, acc[0][1],0,0,0); \
    acc[0][2] = __builtin_amdgcn_mfma_f32_16x16x32_bf16(a0, b2, acc[0][2],0,0,0); \
    acc[0][3] = __builtin_amdgcn_mfma_f32_16x16x32_bf16(a0, b3, acc[0][3],0,0,0); \
    acc[1][0] = __builtin_amdgcn_mfma_f32_16x16x32_bf16(a1, b0, acc[1][0],0,0,0); \
    acc[1][1] = __builtin_amdgcn_mfma_f32_16x16x32_bf16(a1, b1, acc[1][1],0,0,0); \
    acc[1][2] = __builtin_amdgcn_mfma_f32_16x16x32_bf16(a1, b2, acc[1][2],0,0,0); \
    acc[1][3] = __builtin_amdgcn_mfma_f32_16x16x32_bf16(a1, b3, acc[1][3],0,0,0); \
} while(0)

// Fused per-step (R18 structure): blocks [0,128) = node t-1 (reads CHUNKED h of
// step t-1, vectorized); [128,1152) = edge t. Single h write per step.
__global__ __launch_bounds__(512) void k_fused(
    const unsigned short* __restrict__ xenc_t,
    const unsigned short* __restrict__ h_in, unsigned short* __restrict__ h_out,
    unsigned short* __restrict__ c_b,
    const unsigned short* __restrict__ s_wHi, const float* __restrict__ s_bs,
    const unsigned short* __restrict__ t_wHi, const float* __restrict__ t_bs,
    int has_node, int n_edge,
    const float* __restrict__ nodes_prev, const unsigned short* __restrict__ h_node,
    float* __restrict__ h_nn, float* __restrict__ c_nn, float* __restrict__ out_prev,
    const float* __restrict__ att_t_w, const float* __restrict__ att_t_b,
    const float* __restrict__ att_s_w, const float* __restrict__ att_s_b,
    const float* __restrict__ n_enc_w, const float* __restrict__ n_enc_b,
    const float* __restrict__ n_attn_w, const float* __restrict__ n_attn_b,
    const float* __restrict__ n_wT, const float* __restrict__ n_bsum,
    const float* __restrict__ out_w, const float* __restrict__ out_b)
{
    __shared__ __align__(16) char smem[32768];
    const int bid = blockIdx.x, tid = threadIdx.x;

    if (bid < NN) {
        // ================= node path (step t-1), 512 threads, chunked h =========
        if (!has_node) return;
        const int i = bid;
        float* sm  = (float*)smem;
        float* ht  = sm;           float* te  = sm + 256;
        float* u   = sm + 320;     float* lg  = sm + 576;
        float* cat = sm + 704;     float* xc  = sm + 1216;
        float* hnl = sm + 1344;    float* gl  = sm + 1472;
        float* pws = sm + 1984;    float* msc = sm + 4032;

        if (tid < 256) ht[tid] = b2f(h_node[hoff(16256 + i, tid)]);
        __syncthreads();
        if (tid < 256) {            // te: 4 threads per row m
            int m = tid >> 2, q = tid & 3;
            float s = 0.f;
            const float* wr = att_t_w + m*ERNN + q*64;
            const float* hh = ht + q*64;
            #pragma unroll 8
            for (int k = 0; k < 64; ++k) s = fmaf(wr[k], hh[k], s);
            s += __shfl_xor(s, 1);
            s += __shfl_xor(s, 2);
            if (q == 0) te[m] = s + att_t_b[m];
        }
        __syncthreads();
        if (tid < 256) {            // u = att_s_w^T te
            float s = 0.f;
            for (int m = 0; m < 64; ++m) s = fmaf(att_s_w[m*ERNN + tid], te[m], s);
            u[tid] = s;
        }
        if (tid == 320) {
            float s = 0.f;
            for (int m = 0; m < 64; ++m) s = fmaf(te[m], att_s_b[m], s);
            msc[2] = s;
        }
        __syncthreads();
        {                           // logits: 4 threads per slot; chunked 16B loads
            int slot = tid >> 2, q = tid & 3;
            float part = 0.f;
            if (slot < 127) {
                int r = i*127 + slot;
                const unsigned short* hs = h_node
                    + ((size_t)((r>>7)*32 + q*8))*1024 + (size_t)(r&127)*8;
                const float* uu = u + q*64;
                #pragma unroll
                for (int d8 = 0; d8 < 8; ++d8) {
                    bf16x8 v = *(const bf16x8*)(hs + (size_t)d8*1024);
                    #pragma unroll
                    for (int j = 0; j < 8; ++j)
                        part = fmaf(uu[d8*8 + j], b2f((unsigned short)v[j]), part);
                }
            }
            part += __shfl_xor(part, 1);
            part += __shfl_xor(part, 2);
            if (slot < 127 && q == 0) lg[slot] = (part + msc[2]) * TEMPSC;
            if (tid == 511) lg[127] = -1e30f;
        }
        __syncthreads();
        if (tid < 64) {
            float a = fmaxf(lg[tid], lg[tid+64]);
            for (int off = 32; off; off >>= 1) a = fmaxf(a, __shfl_xor(a, off));
            if (tid == 0) msc[0] = a;
        }
        __syncthreads();
        if (tid < 128) lg[tid] = (tid < 127) ? __expf(lg[tid] - msc[0]) : 0.f;
        __syncthreads();
        if (tid < 64) {
            float a = lg[tid] + lg[tid+64];
            for (int off = 32; off; off >>= 1) a += __shfl_xor(a, off);
            if (tid == 0) msc[1] = a;
        }
        __syncthreads();
        {                           // weighted sum: 8 waves x 16 slots; chunked 8B loads
            int w = tid >> 6, lane = tid & 63;
            int cchunk = (lane*4) >> 3, coff = (lane*4) & 7;
            float a0 = 0.f, a1 = 0.f, a2 = 0.f, a3 = 0.f;
            #pragma unroll 4
            for (int s = w*16; s < w*16 + 16; ++s) {
                int srow = (s < 127) ? s : 0;
                float wgt = lg[s];
                int r = i*127 + srow;
                const unsigned short* hp = h_node
                    + ((size_t)((r>>7)*32 + cchunk))*1024 + (size_t)(r&127)*8 + coff;
                ushort4 v = *(const ushort4*)hp;
                a0 = fmaf(wgt, b2f(v.x), a0);
                a1 = fmaf(wgt, b2f(v.y), a1);
                a2 = fmaf(wgt, b2f(v.z), a2);
                a3 = fmaf(wgt, b2f(v.w), a3);
            }
            pws[w*256 + lane*4+0] = a0; pws[w*256 + lane*4+1] = a1;
            pws[w*256 + lane*4+2] = a2; pws[w*256 + lane*4+3] = a3;
        }
        if (tid >= 256 && tid < 384) hnl[tid-256] = h_nn[i*128 + (tid-256)];
        __syncthreads();
        if (tid < 256) {
            float s = 0.f;
            #pragma unroll
            for (int w = 0; w < 8; ++w) s += pws[w*256 + tid];
            cat[256 + tid] = s / msc[1];
            cat[tid] = ht[tid];
        }
        __syncthreads();
        if (tid < 64) {             // enc -> xc[0:64]
            float p0 = nodes_prev[i*2], p1 = nodes_prev[i*2+1];
            xc[tid] = fmaxf(fmaf(n_enc_w[tid*2], p0, fmaf(n_enc_w[tid*2+1], p1, n_enc_b[tid])), 0.f);
        }
        if (tid >= 256) {           // h_emb: 4 threads per row m -> xc[64:128]
            int t2 = tid - 256;
            int m = t2 >> 2, q = t2 & 3;
            float s = 0.f;
            const float* wr = n_attn_w + m*512 + q*128;
            const float* cc = cat + q*128;
            #pragma unroll 8
            for (int d = 0; d < 128; ++d) s = fmaf(wr[d], cc[d], s);
            s += __shfl_xor(s, 1);
            s += __shfl_xor(s, 2);
            if (q == 0) xc[64 + m] = fmaxf(s + n_attn_b[m], 0.f);
        }
        __syncthreads();
        {                           // node LSTM gates: one thread per gate-channel
            int n = tid;
            float s = n_bsum[n];
            for (int k = 0; k < 128; ++k) s = fmaf(n_wT[k*512 + n], xc[k], s);
            for (int k = 0; k < 128; ++k) s = fmaf(n_wT[(128+k)*512 + n], hnl[k], s);
            gl[n] = s;
        }
        __syncthreads();
        if (tid < 128) {
            float co = c_nn[i*128 + tid];
            float c2 = sigm(gl[128+tid])*co + sigm(gl[tid])*ftanh(gl[256+tid]);
            float h2 = sigm(gl[384+tid])*ftanh(c2);
            c_nn[i*128+tid] = c2;
            h_nn[i*128+tid] = h2;
            hnl[tid] = h2;
        }
        __syncthreads();
        if (tid < 5) {
            float s = out_b[tid];
            const float* wr = out_w + tid*128;
            for (int k = 0; k < 128; ++k) s = fmaf(wr[k], hnl[k], s);
            out_prev[i*5 + tid] = s;
        }
        return;
    }

    // ================= edge path (step t), 512 threads, dbuf pipeline ====
    if (!n_edge) return;
    unsigned short (*Ah)[4096] = (unsigned short(*)[4096])smem;            // 2x8KB
    unsigned short (*Bh)[4096] = (unsigned short(*)[4096])(smem + 16384);  // 2x8KB
    const int ebid = bid - NN;
    const int lane = tid & 63, wid = tid >> 6;
    const int wg = (ebid & 7)*128 + (ebid >> 3);   // XCD swizzle, bijective on 1024
    const int bm = wg >> 3, ntp = wg & 7;          // 128 bm x 8 col-pairs
    const bool sp = (bm < 127);
    const int rbase = bm * 128;
    const unsigned short* wHi = sp ? s_wHi : t_wHi;
    const float* bs = sp ? s_bs : t_bs;
    const int wr = wid & 3, wc = wid >> 2;         // row-group, col-half
    const int nt = ntp*2 + wc;                     // [0,16) 64-col group

    // staging into buffer b: wave w covers (kc=w>>1, half=w&1) -> 2 contiguous-1KB glds
    auto stage = [&](int ks, int b){
        int kc = wid >> 1, half = wid & 1;
        const unsigned short* asrc = (ks < 2)
            ? xenc_t + ((size_t)bm*8  + ks*4     + kc)*1024 + half*512
            : h_in   + ((size_t)bm*32 + (ks-2)*4 + kc)*1024 + half*512;
        glds16(asrc + lane*8, (char*)&Ah[b][0] + wid*1024);
        size_t wb = ((size_t)(ntp*40 + ks*4 + kc)*128 + half*64)*8;
        glds16(wHi + wb + lane*8, (char*)&Bh[b][0] + wid*1024);
    };
    stage(0, 0);
    stage(1, 1);

    f32x4 acc[2][4];
    #pragma unroll
    for (int m = 0; m < 2; ++m)
        #pragma unroll
        for (int g = 0; g < 4; ++g)
            acc[m][g] = (f32x4){0.f,0.f,0.f,0.f};

    const int arow = wr*32 + (lane & 15);
    const int bcol = wc*64 + (lane & 15);
    const int kg = lane >> 4;

    ESTEP(0, 2);
    ESTEP(1, 2);
    ESTEP(2, 2);
    ESTEP(3, 2);
    ESTEP(4, 2);
    ESTEP(5, 2);
    ESTEP(6, 2);
    ESTEP(7, 2);
    ESTEP(8, 2);
    ESTEP(9, 0);

    const int chl = lane & 15, q4 = (lane >> 4)*4;
    const int ch = nt*16 + chl;
    const int cbase = nt*64 + chl;
    const float b0 = bs[cbase], b1 = bs[cbase+16], b2 = bs[cbase+32], b3 = bs[cbase+48];
    #pragma unroll
    for (int m = 0; m < 2; ++m) {
        #pragma unroll
        for (int rg = 0; rg < 4; ++rg) {
            int lrow = wr*32 + m*16 + q4 + rg;
            int row = rbase + lrow;
            float gi = acc[m][0][rg] + b0;
            float gf = acc[m][1][rg] + b1;
            float gg = acc[m][2][rg] + b2;
            float go = acc[m][3][rg] + b3;
            size_t off = (size_t)row*256 + ch;
            float c_old = b2f(c_b[off]);
            float c2 = sigm(gf)*c_old + sigm(gi)*ftanh(gg);
            float h2 = sigm(go)*ftanh(c2);
            c_b[off] = f2b(c2);
            h_out[((size_t)(bm*32 + (ch>>3))*128 + lrow)*8 + (ch&7)] = f2b(h2);
        }
    }
}

extern "C" void kernel_launch(void* const* d_in, const int* in_sizes, int n_in,
                              void* d_out, int out_size, void* d_ws, size_t ws_size,
                              hipStream_t stream)
{
    const float* nodes   = (const float*)d_in[0];
    const float* edges   = (const float*)d_in[1];
    const float* h_e0    = (const float*)d_in[2];
    const float* c_e0    = (const float*)d_in[3];
    const float* h_n0    = (const float*)d_in[4];
    const float* c_n0    = (const float*)d_in[5];
    const float* t_enc_w = (const float*)d_in[6];
    const float* t_enc_b = (const float*)d_in[7];
    const float* t_wih   = (const float*)d_in[8];
    const float* t_whh   = (const float*)d_in[9];
    const float* t_bih   = (const float*)d_in[10];
    const float* t_bhh   = (const float*)d_in[11];
    const float* s_enc_w = (const float*)d_in[12];
    const float* s_enc_b = (const float*)d_in[13];
    const float* s_wih   = (const float*)d_in[14];
    const float* s_whh   = (const float*)d_in[15];
    const float* s_bih   = (const float*)d_in[16];
    const float* s_bhh   = (const float*)d_in[17];
    const float* att_t_w = (const float*)d_in[18];
    const float* att_t_b = (const float*)d_in[19];
    const float* att_s_w = (const float*)d_in[20];
    const float* att_s_b = (const float*)d_in[21];
    const float* n_enc_w = (const float*)d_in[22];
    const float* n_enc_b = (const float*)d_in[23];
    const float* n_attn_w= (const float*)d_in[24];
    const float* n_attn_b= (const float*)d_in[25];
    const float* n_wih   = (const float*)d_in[26];
    const float* n_whh   = (const float*)d_in[27];
    const float* n_bih   = (const float*)d_in[28];
    const float* n_bhh   = (const float*)d_in[29];
    const float* out_w   = (const float*)d_in[30];
    const float* out_b   = (const float*)d_in[31];
    float* out = (float*)d_out;

    char* p = (char*)d_ws;
    float* h_nn  = (float*)p;            p += 128*128*4;
    float* c_nn  = (float*)p;            p += 128*128*4;
    float* s_bs  = (float*)p;            p += 1024*4;
    float* t_bs  = (float*)p;            p += 1024*4;
    float* n_wT  = (float*)p;            p += 256*512*4;
    float* n_bs  = (float*)p;            p += 512*4;
    unsigned short* c_b  = (unsigned short*)p;  p += (size_t)16384*256*2;
    unsigned short* h_a  = (unsigned short*)p;  p += (size_t)16384*256*2;
    unsigned short* h_b  = (unsigned short*)p;  p += (size_t)16384*256*2;
    unsigned short* xenc = (unsigned short*)p;  p += (size_t)TT*16384*64*2;
    unsigned short* s_wHi = (unsigned short*)p; p += 1024*320*2;
    unsigned short* t_wHi = (unsigned short*)p; p += 1024*320*2;

    int prep_blocks = (int)((PREP_TOT + 255) / 256);
    k_prep_all<<<prep_blocks, 256, 0, stream>>>(
        s_wih, s_whh, s_wHi, t_wih, t_whh, t_wHi,
        s_bih, s_bhh, s_bs, t_bih, t_bhh, t_bs,
        n_wih, n_whh, n_wT, n_bih, n_bhh, n_bs,
        h_n0, h_nn, c_n0, c_nn,
        h_e0, c_e0, h_a, c_b,
        edges, s_enc_w, s_enc_b, t_enc_w, t_enc_b, xenc);

    for (int t = 0; t < TT; ++t) {
        const unsigned short* h_in  = (t & 1) ? h_b : h_a;   // h(t-1), chunked
        unsigned short*       h_out = (t & 1) ? h_a : h_b;
        const float* nprev = (t > 0) ? nodes + (size_t)(t-1)*NN*2 : nodes;
        float* oprev = (t > 0) ? out + (size_t)(t-1)*NN*5 : out;
        k_fused<<<NN + 1024, 512, 0, stream>>>(xenc + (size_t)t*16384*64,
            h_in, h_out, c_b,
            s_wHi, s_bs, t_wHi, t_bs,
            (t > 0) ? 1 : 0, 1024,
            nprev, h_in, h_nn, c_nn, oprev,
            att_t_w, att_t_b, att_s_w, att_s_b, n_enc_w, n_enc_b,
            n_attn_w, n_attn_b, n_wT, n_bs, out_w, out_b);
    }
    // final node step (t = 19): reads h(19) = h_out of step 19 (t=19 odd -> h_a)
    k_fused<<<NN, 512, 0, stream>>>(xenc,
        h_a, h_b, c_b,
        s_wHi, s_bs, t_wHi, t_bs,
        1, 0,
        nodes + (size_t)19*NN*2, h_a, h_nn, c_nn, out + (size_t)19*NN*5,
        att_t_w, att_t_b, att_s_w, att_s_b, n_enc_w, n_enc_b,
        n_attn_w, n_attn_b, n_wT, n_bs, out_w, out_b);
}